// Round 7
// baseline (1079.306 us; speedup 1.0000x reference)
//
#include <hip/hip_runtime.h>
#include <hip/hip_bf16.h>
#include <math.h>

#define SHIFT_ 4

typedef __attribute__((ext_vector_type(8))) short bh8;
typedef __attribute__((ext_vector_type(4))) short sh4;
typedef __attribute__((ext_vector_type(4))) float f4;
typedef __attribute__((ext_vector_type(8))) __bf16 bf8t;

static __device__ __forceinline__ f4 mfma16(bh8 a, bh8 b, f4 c){
  return __builtin_amdgcn_mfma_f32_16x16x32_bf16(
    __builtin_bit_cast(bf8t, a), __builtin_bit_cast(bf8t, b), c, 0, 0, 0);
}
static __device__ __forceinline__ unsigned short f2b(float f){
  unsigned u = __builtin_bit_cast(unsigned, f);
  u += 0x7fffu + ((u >> 16) & 1u);
  return (unsigned short)(u >> 16);
}
static __device__ __forceinline__ float b2f(unsigned short h){
  return __builtin_bit_cast(float, ((unsigned)h) << 16);
}
static __device__ __forceinline__ unsigned cvt_pk_bf16(float lo, float hi){
  unsigned r;
  asm("v_cvt_pk_bf16_f32 %0, %1, %2" : "=v"(r) : "v"(lo), "v"(hi));
  return r;
}

// ---------------- kernel 0: weights f32 -> bf16 (qw pre-scaled by d^-0.5) ---
__global__ __launch_bounds__(256) void prep_w(
    const float* __restrict__ qw, const float* __restrict__ kvw,
    const float* __restrict__ pw, const float* __restrict__ w1,
    const float* __restrict__ w2, unsigned short* __restrict__ wb){
  int i = blockIdx.x * 256 + threadIdx.x;   // 786432 total
  float v;
  if      (i < 65536)  v = qw[i] * 0.17677669529663687f;
  else if (i < 196608) v = kvw[i - 65536];
  else if (i < 262144) v = pw[i - 196608];
  else if (i < 524288) v = w1[i - 262144];
  else                 v = w2[i - 524288];
  wb[i] = f2b(v);
}

// ---------------- kernel 1: LN1 + roll(-4,-4) + window partition ------------
__global__ __launch_bounds__(256) void ln1_win(
    const float* __restrict__ x, const float* __restrict__ g1,
    const float* __restrict__ b1,
    unsigned short* __restrict__ q_in, unsigned short* __restrict__ kv_in){
  int rid  = blockIdx.x * 4 + (threadIdx.x >> 6);   // 0..262143
  int lane = threadIdx.x & 63;
  int d    = rid >> 17;
  int rem  = rid & 131071;          // w*64 + n
  int w = rem >> 6, n = rem & 63;
  int b = w >> 10, hb = (w >> 5) & 31, wbk = w & 31;
  int sh = (hb * 8 + (n >> 3) + SHIFT_) & 255;
  int sw = (wbk * 8 + (n & 7) + SHIFT_) & 255;
  const float* src = x + ((((size_t)(b * 2 + d)) * 256 + sh) * 256 + sw) * 256;
  float4 v = *(const float4*)(src + lane * 4);
  float s  = v.x + v.y + v.z + v.w;
  float ss = v.x * v.x + v.y * v.y + v.z * v.z + v.w * v.w;
  #pragma unroll
  for (int off = 1; off < 64; off <<= 1){ s += __shfl_xor(s, off); ss += __shfl_xor(ss, off); }
  float m    = s * (1.f / 256.f);
  float rstd = rsqrtf(ss * (1.f / 256.f) - m * m + 1e-5f);
  int c = lane * 4;
  float4 g  = *(const float4*)(g1 + c);
  float4 bb = *(const float4*)(b1 + c);
  sh4 o;
  o.x = (short)f2b((v.x - m) * rstd * g.x + bb.x);
  o.y = (short)f2b((v.y - m) * rstd * g.y + bb.y);
  o.z = (short)f2b((v.z - m) * rstd * g.z + bb.z);
  o.w = (short)f2b((v.w - m) * rstd * g.w + bb.w);
  unsigned short* dst = (d == 0 ? q_in : kv_in) + (size_t)rem * 256 + c;
  *(sh4*)dst = o;
}

// ---------------- generic GEMM: C = A(Mx256) @ W^T (+bias), 3 epilogues -----
// LDS stride 74 shorts = 37 banks (odd mod 32) -> frag reads ~conflict-free.
template<int MODE>
__global__ __launch_bounds__(256) void gemm_bt(
    const unsigned short* __restrict__ A, const unsigned short* __restrict__ Wt,
    const float* __restrict__ bias, float bias_scale,
    unsigned short* __restrict__ outb, unsigned short* __restrict__ vt,
    float* __restrict__ outf, const unsigned short* __restrict__ qin,
    const float* __restrict__ xsrc){
  __shared__ unsigned short sA[128][74];
  __shared__ unsigned short sB[128][74];
  int m0 = blockIdx.x * 128, n0 = blockIdx.y * 128;
  int tid = threadIdx.x;
  int lane = tid & 63, wid = tid >> 6;
  int wm = wid >> 1, wn = wid & 1;
  int llo = lane & 15, lhi = lane >> 4;
  f4 acc[4][4];
  const f4 FZ = {0.f, 0.f, 0.f, 0.f};
  for (int i = 0; i < 4; i++) for (int j = 0; j < 4; j++) acc[i][j] = FZ;

  for (int k0 = 0; k0 < 256; k0 += 64){
    #pragma unroll
    for (int i = 0; i < 4; i++){
      int li = tid + i * 256;           // 0..1023
      int r = li >> 3, ck = li & 7;
      *(bh8*)&sA[r][ck * 8] = *(const bh8*)(A  + (size_t)(m0 + r) * 256 + k0 + ck * 8);
      *(bh8*)&sB[r][ck * 8] = *(const bh8*)(Wt + (size_t)(n0 + r) * 256 + k0 + ck * 8);
    }
    __syncthreads();
    #pragma unroll
    for (int ks = 0; ks < 2; ks++){
      bh8 a[4], b[4];
      #pragma unroll
      for (int mi = 0; mi < 4; mi++) a[mi] = *(const bh8*)&sA[wm * 64 + mi * 16 + llo][ks * 32 + lhi * 8];
      #pragma unroll
      for (int nj = 0; nj < 4; nj++) b[nj] = *(const bh8*)&sB[wn * 64 + nj * 16 + llo][ks * 32 + lhi * 8];
      #pragma unroll
      for (int mi = 0; mi < 4; mi++)
        #pragma unroll
        for (int nj = 0; nj < 4; nj++)
          acc[mi][nj] = mfma16(a[mi], b[nj], acc[mi][nj]);
    }
    __syncthreads();
  }
  #pragma unroll
  for (int mi = 0; mi < 4; mi++)
    for (int nj = 0; nj < 4; nj++){
      int col = n0 + wn * 64 + nj * 16 + llo;
      float bv = bias[col] * bias_scale;
      #pragma unroll
      for (int r = 0; r < 4; r++){
        int row = m0 + wm * 64 + mi * 16 + lhi * 4 + r;
        float val = acc[mi][nj][r] + bv;
        if (MODE == 0){
          outb[(size_t)row * 256 + col] = f2b(val);
        } else if (MODE == 1){
          if (col < 256) outb[(size_t)row * 256 + col] = f2b(val);
          else {
            int cv = col - 256, hd = cv >> 5, dd = cv & 31;
            int w = row >> 6, n = row & 63;
            vt[(((size_t)w * 8 + hd) * 32 + dd) * 64 + n] = f2b(val);
          }
        } else {
          int w = row >> 6, n = row & 63;
          int b = w >> 10, hb = (w >> 5) & 31, wbk = w & 31;
          int hh = (hb * 8 + (n >> 3) + SHIFT_) & 255;
          int ww = (wbk * 8 + (n & 7) + SHIFT_) & 255;
          float res = b2f(qin[(size_t)row * 256 + col]);
          float sc  = xsrc[((((size_t)(b * 2)) * 256 + hh) * 256 + ww) * 256 + col];
          outf[(((size_t)b * 256 + hh) * 256 + ww) * 256 + col] = val + res + sc;
        }
      }
    }
}

// ---------------- kernel 3: per (window, head) attention --------------------
// strides: sQ/sK 42 (21 banks), sVT/sP 74 (37 banks) -> odd mod 32.
__global__ __launch_bounds__(64) void attn_k(
    const unsigned short* __restrict__ q, const unsigned short* __restrict__ k,
    const unsigned short* __restrict__ vt, const float* __restrict__ mask,
    const float* __restrict__ bias_table, unsigned short* __restrict__ aout){
  __shared__ unsigned short sQ[64][42];
  __shared__ unsigned short sK[64][42];
  __shared__ unsigned short sVT[32][74];
  __shared__ unsigned short sP[64][74];
  __shared__ float sBias[225];
  int bid = blockIdx.x;
  int w = bid >> 3, hd = bid & 7;
  int lane = threadIdx.x;
  int llo = lane & 15, lhi = lane >> 4;
  for (int i = lane; i < 225; i += 64) sBias[i] = bias_table[i * 8 + hd];
  {
    const unsigned short* qp = q + ((size_t)w * 64 + lane) * 256 + hd * 32;
    const unsigned short* kp = k + ((size_t)w * 64 + lane) * 256 + hd * 32;
    #pragma unroll
    for (int c2 = 0; c2 < 4; c2++){
      *(bh8*)&sQ[lane][c2 * 8] = *(const bh8*)(qp + c2 * 8);
      *(bh8*)&sK[lane][c2 * 8] = *(const bh8*)(kp + c2 * 8);
    }
    const unsigned short* vp = vt + (((size_t)w * 8 + hd) * 32 + (lane >> 1)) * 64 + (lane & 1) * 32;
    #pragma unroll
    for (int c2 = 0; c2 < 4; c2++)
      *(bh8*)&sVT[lane >> 1][(lane & 1) * 32 + c2 * 8] = *(const bh8*)(vp + c2 * 8);
  }
  __syncthreads();
  const f4 FZ = {0.f, 0.f, 0.f, 0.f};
  f4 acc[4][4];
  {
    bh8 a[4], b[4];
    #pragma unroll
    for (int mi = 0; mi < 4; mi++) a[mi] = *(const bh8*)&sQ[mi * 16 + llo][lhi * 8];
    #pragma unroll
    for (int nj = 0; nj < 4; nj++) b[nj] = *(const bh8*)&sK[nj * 16 + llo][lhi * 8];
    #pragma unroll
    for (int mi = 0; mi < 4; mi++)
      #pragma unroll
      for (int nj = 0; nj < 4; nj++)
        acc[mi][nj] = mfma16(a[mi], b[nj], FZ);
  }
  const float* mrow = mask + (size_t)(w & 1023) * 4096;
  #pragma unroll
  for (int mi = 0; mi < 4; mi++){
    #pragma unroll
    for (int r = 0; r < 4; r++){
      int rr = mi * 16 + lhi * 4 + r;
      int yi = rr >> 3, xi = rr & 7;
      float sv[4]; float mx = -1e30f;
      #pragma unroll
      for (int nj = 0; nj < 4; nj++){
        int cc = nj * 16 + llo;
        int idx = (yi - (cc >> 3) + 7) * 15 + (xi - (cc & 7) + 7);
        sv[nj] = acc[mi][nj][r] + sBias[idx] + mrow[rr * 64 + cc];
        mx = fmaxf(mx, sv[nj]);
      }
      #pragma unroll
      for (int off = 1; off < 16; off <<= 1) mx = fmaxf(mx, __shfl_xor(mx, off));
      float sum = 0.f;
      #pragma unroll
      for (int nj = 0; nj < 4; nj++){ sv[nj] = __expf(sv[nj] - mx); sum += sv[nj]; }
      #pragma unroll
      for (int off = 1; off < 16; off <<= 1) sum += __shfl_xor(sum, off);
      float inv = __builtin_amdgcn_rcpf(sum);
      #pragma unroll
      for (int nj = 0; nj < 4; nj++) sP[rr][nj * 16 + llo] = f2b(sv[nj] * inv);
    }
  }
  __syncthreads();
  f4 o[4][2];
  for (int mi = 0; mi < 4; mi++) for (int dj = 0; dj < 2; dj++) o[mi][dj] = FZ;
  #pragma unroll
  for (int ks = 0; ks < 2; ks++){
    bh8 pa[4], vb[2];
    #pragma unroll
    for (int mi = 0; mi < 4; mi++) pa[mi] = *(const bh8*)&sP[mi * 16 + llo][ks * 32 + lhi * 8];
    #pragma unroll
    for (int dj = 0; dj < 2; dj++) vb[dj] = *(const bh8*)&sVT[dj * 16 + llo][ks * 32 + lhi * 8];
    #pragma unroll
    for (int mi = 0; mi < 4; mi++)
      #pragma unroll
      for (int dj = 0; dj < 2; dj++)
        o[mi][dj] = mfma16(pa[mi], vb[dj], o[mi][dj]);
  }
  #pragma unroll
  for (int mi = 0; mi < 4; mi++)
    for (int dj = 0; dj < 2; dj++)
      for (int r = 0; r < 4; r++){
        int rr = mi * 16 + lhi * 4 + r, dd = dj * 16 + llo;
        aout[((size_t)w * 64 + rr) * 256 + hd * 32 + dd] = f2b(o[mi][dj][r]);
      }
}

// ---------------- kernel 5: fused LN2 + MLP (+residual), in-place on d_out --
// v8 = v7 + double-buffered sH (ONE barrier per hc, 8 total; GEMM2(hc) and
// GEMM1(hc+1) run back-to-back between barriers = 128 MFMAs/phase) + odd-bank
// LDS strides (266/138) killing the 8-way frag-read conflicts.
__global__ __launch_bounds__(256, 2) void mlp_k(
    float* __restrict__ x1, const float* __restrict__ g2,
    const float* __restrict__ b2, const unsigned short* __restrict__ w1b,
    const float* __restrict__ bi1, const unsigned short* __restrict__ w2b,
    const float* __restrict__ bi2){
  __shared__ unsigned short sX[64][266];
  __shared__ unsigned short sH[2][64][138];
  int rb = blockIdx.x * 64;
  int tid = threadIdx.x, lane = tid & 63, wid = tid >> 6;   // 4 waves
  int llo = lane & 15, lhi = lane >> 4;
  for (int rr = wid; rr < 64; rr += 4){
    const float* xr = x1 + ((size_t)rb + rr) * 256;
    float4 v = *(const float4*)(xr + lane * 4);
    float s  = v.x + v.y + v.z + v.w;
    float ss = v.x * v.x + v.y * v.y + v.z * v.z + v.w * v.w;
    #pragma unroll
    for (int off = 1; off < 64; off <<= 1){ s += __shfl_xor(s, off); ss += __shfl_xor(ss, off); }
    float m    = s * (1.f / 256.f);
    float rstd = rsqrtf(ss * (1.f / 256.f) - m * m + 1e-5f);
    int c = lane * 4;
    float4 g  = *(const float4*)(g2 + c);
    float4 bb = *(const float4*)(b2 + c);
    sh4 o;
    o.x = (short)f2b((v.x - m) * rstd * g.x + bb.x);
    o.y = (short)f2b((v.y - m) * rstd * g.y + bb.y);
    o.z = (short)f2b((v.z - m) * rstd * g.z + bb.z);
    o.w = (short)f2b((v.w - m) * rstd * g.w + bb.w);
    *(sh4*)&sX[rr][c] = o;
  }
  __syncthreads();
  const f4 FZ = {0.f, 0.f, 0.f, 0.f};
  f4 acc2[4][4];
  for (int i = 0; i < 4; i++) for (int j = 0; j < 4; j++) acc2[i][j] = FZ;
  // GEMM1 B-frag rows = hidden (wave covers 32 hidden of the 128-chunk)
  const unsigned short* w1t = w1b + (size_t)(wid * 32 + llo) * 256 + lhi * 8;
  // GEMM2 B-frag rows = output cols (wave covers 64 of 256)
  const unsigned short* w2t = w2b + (size_t)(wid * 64 + llo) * 1024 + lhi * 8;
  for (int hc = 0; hc < 8; hc++){
    // ---- GEMM1 (swapped): acc1[nj][mi], hidden idx = lhi*4+r ----
    f4 acc1[2][4];
    for (int i = 0; i < 2; i++) for (int j = 0; j < 4; j++) acc1[i][j] = FZ;
    const unsigned short* w1p = w1t + (size_t)hc * 32768;   // hc*128 rows * 256
    #pragma unroll
    for (int ks = 0; ks < 8; ks++){
      bh8 a[4], b[2];
      #pragma unroll
      for (int mi = 0; mi < 4; mi++) a[mi] = *(const bh8*)&sX[mi * 16 + llo][ks * 32 + lhi * 8];
      #pragma unroll
      for (int nj = 0; nj < 2; nj++) b[nj] = *(const bh8*)(w1p + nj * 4096 + ks * 32);
      #pragma unroll
      for (int nj = 0; nj < 2; nj++)
        #pragma unroll
        for (int mi = 0; mi < 4; mi++)
          acc1[nj][mi] = mfma16(b[nj], a[mi], acc1[nj][mi]);
    }
    // epilogue -> sH[hc&1] (write-before-barrier; reads of this buffer were
    // drained at the previous barrier)
    #pragma unroll
    for (int nj = 0; nj < 2; nj++){
      int ocb = wid * 32 + nj * 16 + lhi * 4;      // 4 consecutive hidden
      float4 bv = *(const float4*)(bi1 + hc * 128 + ocb);
      #pragma unroll
      for (int mi = 0; mi < 4; mi++){
        float gv[4];
        float hv0 = acc1[nj][mi][0] + bv.x;
        float hv1 = acc1[nj][mi][1] + bv.y;
        float hv2 = acc1[nj][mi][2] + bv.z;
        float hv3 = acc1[nj][mi][3] + bv.w;
        #pragma unroll
        for (int r = 0; r < 4; r++){
          float hv = (r==0?hv0:r==1?hv1:r==2?hv2:hv3);
          float u = hv * (1.5957691216f + 0.0713548162f * hv * hv);
          gv[r] = hv * __builtin_amdgcn_rcpf(1.f + __expf(-u));
        }
        uint2 p;
        p.x = cvt_pk_bf16(gv[0], gv[1]);
        p.y = cvt_pk_bf16(gv[2], gv[3]);
        *(uint2*)&sH[hc & 1][mi * 16 + llo][ocb] = p;
      }
    }
    __syncthreads();   // single barrier per hc
    // ---- GEMM2: out += gelu(H) @ W2_chunk^T ----
    const unsigned short* w2p = w2t + hc * 128;
    #pragma unroll
    for (int ks = 0; ks < 4; ks++){
      bh8 a[4], c[4];
      #pragma unroll
      for (int mi = 0; mi < 4; mi++) a[mi] = *(const bh8*)&sH[hc & 1][mi * 16 + llo][ks * 32 + lhi * 8];
      #pragma unroll
      for (int nj = 0; nj < 4; nj++) c[nj] = *(const bh8*)(w2p + nj * 16384 + ks * 32);
      #pragma unroll
      for (int mi = 0; mi < 4; mi++)
        #pragma unroll
        for (int nj = 0; nj < 4; nj++)
          acc2[mi][nj] = mfma16(a[mi], c[nj], acc2[mi][nj]);
    }
  }
  #pragma unroll
  for (int mi = 0; mi < 4; mi++)
    #pragma unroll
    for (int nj = 0; nj < 4; nj++){
      int c2 = wid * 64 + nj * 16 + llo;
      float bv = bi2[c2];
      #pragma unroll
      for (int r = 0; r < 4; r++){
        size_t idx = ((size_t)rb + mi * 16 + lhi * 4 + r) * 256 + c2;
        x1[idx] += acc2[mi][nj][r] + bv;
      }
    }
}

extern "C" void kernel_launch(void* const* d_in, const int* in_sizes, int n_in,
                              void* d_out, int out_size, void* d_ws, size_t ws_size,
                              hipStream_t stream){
  const float* x          = (const float*)d_in[0];
  const float* mask       = (const float*)d_in[1];
  const float* g1         = (const float*)d_in[2];
  const float* b1         = (const float*)d_in[3];
  const float* qw         = (const float*)d_in[4];
  const float* qb         = (const float*)d_in[5];
  const float* kvw        = (const float*)d_in[6];
  const float* kvb        = (const float*)d_in[7];
  const float* pw         = (const float*)d_in[8];
  const float* pb         = (const float*)d_in[9];
  const float* bias_table = (const float*)d_in[10];
  const float* g2         = (const float*)d_in[11];
  const float* b2         = (const float*)d_in[12];
  const float* w1         = (const float*)d_in[13];
  const float* bi1        = (const float*)d_in[14];
  const float* w2         = (const float*)d_in[15];
  const float* bi2        = (const float*)d_in[16];
  float* out = (float*)d_out;
  char* ws = (char*)d_ws;
  const long long SEG = 67108864LL;   // 2048*64*256 bf16 bytes
  unsigned short* q_in  = (unsigned short*)(ws);
  unsigned short* kv_in = (unsigned short*)(ws + SEG);
  unsigned short* qbuf  = (unsigned short*)(ws + 2 * SEG);
  unsigned short* kbuf  = (unsigned short*)(ws + 3 * SEG);
  unsigned short* vtb   = (unsigned short*)(ws + 4 * SEG);
  unsigned short* wb    = (unsigned short*)(ws + 5 * SEG);
  unsigned short* aoutb = kv_in;      // kv_in dead after kv GEMM -> alias

  prep_w<<<3072, 256, 0, stream>>>(qw, kvw, pw, w1, w2, wb);
  ln1_win<<<65536, 256, 0, stream>>>(x, g1, b1, q_in, kv_in);
  gemm_bt<0><<<dim3(1024, 2), 256, 0, stream>>>(q_in, wb, qb, 0.17677669529663687f,
                                                qbuf, nullptr, nullptr, nullptr, nullptr);
  gemm_bt<1><<<dim3(1024, 4), 256, 0, stream>>>(kv_in, wb + 65536, kvb, 1.0f,
                                                kbuf, vtb, nullptr, nullptr, nullptr);
  attn_k<<<16384, 64, 0, stream>>>(qbuf, kbuf, vtb, mask, bias_table, aoutb);
  gemm_bt<2><<<dim3(1024, 2), 256, 0, stream>>>(aoutb, wb + 196608, pb, 1.0f,
                                                nullptr, nullptr, out, q_in, x);
  mlp_k<<<2048, 256, 0, stream>>>(out, g2, b2, wb + 262144, bi1, wb + 524288, bi2);
}

// Round 8
// 967.499 us; speedup vs baseline: 1.1156x; 1.1156x over previous
//
#include <hip/hip_runtime.h>
#include <hip/hip_bf16.h>
#include <math.h>

#define SHIFT_ 4

typedef __attribute__((ext_vector_type(8))) short bh8;
typedef __attribute__((ext_vector_type(4))) short sh4;
typedef __attribute__((ext_vector_type(4))) float f4;
typedef __attribute__((ext_vector_type(8))) __bf16 bf8t;

static __device__ __forceinline__ f4 mfma16(bh8 a, bh8 b, f4 c){
  return __builtin_amdgcn_mfma_f32_16x16x32_bf16(
    __builtin_bit_cast(bf8t, a), __builtin_bit_cast(bf8t, b), c, 0, 0, 0);
}
static __device__ __forceinline__ unsigned short f2b(float f){
  unsigned u = __builtin_bit_cast(unsigned, f);
  u += 0x7fffu + ((u >> 16) & 1u);
  return (unsigned short)(u >> 16);
}
static __device__ __forceinline__ float b2f(unsigned short h){
  return __builtin_bit_cast(float, ((unsigned)h) << 16);
}
static __device__ __forceinline__ unsigned cvt_pk_bf16(float lo, float hi){
  unsigned r;
  asm("v_cvt_pk_bf16_f32 %0, %1, %2" : "=v"(r) : "v"(lo), "v"(hi));
  return r;
}
static __device__ __forceinline__ float gelu_f(float hv){
  float u = hv * (1.5957691216f + 0.0713548162f * hv * hv);
  return hv * __builtin_amdgcn_rcpf(1.f + __expf(-u));
}

// ---------------- kernel 0: weights f32 -> bf16 (qw pre-scaled by d^-0.5) ---
__global__ __launch_bounds__(256) void prep_w(
    const float* __restrict__ qw, const float* __restrict__ kvw,
    const float* __restrict__ pw, const float* __restrict__ w1,
    const float* __restrict__ w2, unsigned short* __restrict__ wb){
  int i = blockIdx.x * 256 + threadIdx.x;   // 786432 total
  float v;
  if      (i < 65536)  v = qw[i] * 0.17677669529663687f;
  else if (i < 196608) v = kvw[i - 65536];
  else if (i < 262144) v = pw[i - 196608];
  else if (i < 524288) v = w1[i - 262144];
  else                 v = w2[i - 524288];
  wb[i] = f2b(v);
}

// ---------------- kernel 1: LN1 + roll(-4,-4) + window partition ------------
__global__ __launch_bounds__(256) void ln1_win(
    const float* __restrict__ x, const float* __restrict__ g1,
    const float* __restrict__ b1,
    unsigned short* __restrict__ q_in, unsigned short* __restrict__ kv_in){
  int rid  = blockIdx.x * 4 + (threadIdx.x >> 6);   // 0..262143
  int lane = threadIdx.x & 63;
  int d    = rid >> 17;
  int rem  = rid & 131071;          // w*64 + n
  int w = rem >> 6, n = rem & 63;
  int b = w >> 10, hb = (w >> 5) & 31, wbk = w & 31;
  int sh = (hb * 8 + (n >> 3) + SHIFT_) & 255;
  int sw = (wbk * 8 + (n & 7) + SHIFT_) & 255;
  const float* src = x + ((((size_t)(b * 2 + d)) * 256 + sh) * 256 + sw) * 256;
  float4 v = *(const float4*)(src + lane * 4);
  float s  = v.x + v.y + v.z + v.w;
  float ss = v.x * v.x + v.y * v.y + v.z * v.z + v.w * v.w;
  #pragma unroll
  for (int off = 1; off < 64; off <<= 1){ s += __shfl_xor(s, off); ss += __shfl_xor(ss, off); }
  float m    = s * (1.f / 256.f);
  float rstd = rsqrtf(ss * (1.f / 256.f) - m * m + 1e-5f);
  int c = lane * 4;
  float4 g  = *(const float4*)(g1 + c);
  float4 bb = *(const float4*)(b1 + c);
  sh4 o;
  o.x = (short)f2b((v.x - m) * rstd * g.x + bb.x);
  o.y = (short)f2b((v.y - m) * rstd * g.y + bb.y);
  o.z = (short)f2b((v.z - m) * rstd * g.z + bb.z);
  o.w = (short)f2b((v.w - m) * rstd * g.w + bb.w);
  unsigned short* dst = (d == 0 ? q_in : kv_in) + (size_t)rem * 256 + c;
  *(sh4*)dst = o;
}

// ---------------- generic GEMM: C = A(Mx256) @ W^T (+bias), 3 epilogues -----
template<int MODE>
__global__ __launch_bounds__(256) void gemm_bt(
    const unsigned short* __restrict__ A, const unsigned short* __restrict__ Wt,
    const float* __restrict__ bias, float bias_scale,
    unsigned short* __restrict__ outb, unsigned short* __restrict__ vt,
    float* __restrict__ outf, const unsigned short* __restrict__ qin,
    const float* __restrict__ xsrc){
  __shared__ unsigned short sA[128][72];
  __shared__ unsigned short sB[128][72];
  int m0 = blockIdx.x * 128, n0 = blockIdx.y * 128;
  int tid = threadIdx.x;
  int lane = tid & 63, wid = tid >> 6;
  int wm = wid >> 1, wn = wid & 1;
  int llo = lane & 15, lhi = lane >> 4;
  f4 acc[4][4];
  const f4 FZ = {0.f, 0.f, 0.f, 0.f};
  for (int i = 0; i < 4; i++) for (int j = 0; j < 4; j++) acc[i][j] = FZ;

  for (int k0 = 0; k0 < 256; k0 += 64){
    #pragma unroll
    for (int i = 0; i < 4; i++){
      int li = tid + i * 256;           // 0..1023
      int r = li >> 3, ck = li & 7;
      *(bh8*)&sA[r][ck * 8] = *(const bh8*)(A  + (size_t)(m0 + r) * 256 + k0 + ck * 8);
      *(bh8*)&sB[r][ck * 8] = *(const bh8*)(Wt + (size_t)(n0 + r) * 256 + k0 + ck * 8);
    }
    __syncthreads();
    #pragma unroll
    for (int ks = 0; ks < 2; ks++){
      bh8 a[4], b[4];
      #pragma unroll
      for (int mi = 0; mi < 4; mi++) a[mi] = *(const bh8*)&sA[wm * 64 + mi * 16 + llo][ks * 32 + lhi * 8];
      #pragma unroll
      for (int nj = 0; nj < 4; nj++) b[nj] = *(const bh8*)&sB[wn * 64 + nj * 16 + llo][ks * 32 + lhi * 8];
      #pragma unroll
      for (int mi = 0; mi < 4; mi++)
        #pragma unroll
        for (int nj = 0; nj < 4; nj++)
          acc[mi][nj] = mfma16(a[mi], b[nj], acc[mi][nj]);
    }
    __syncthreads();
  }
  #pragma unroll
  for (int mi = 0; mi < 4; mi++)
    for (int nj = 0; nj < 4; nj++){
      int col = n0 + wn * 64 + nj * 16 + llo;
      float bv = bias[col] * bias_scale;
      #pragma unroll
      for (int r = 0; r < 4; r++){
        int row = m0 + wm * 64 + mi * 16 + lhi * 4 + r;
        float val = acc[mi][nj][r] + bv;
        if (MODE == 0){
          outb[(size_t)row * 256 + col] = f2b(val);
        } else if (MODE == 1){
          if (col < 256) outb[(size_t)row * 256 + col] = f2b(val);
          else {
            int cv = col - 256, hd = cv >> 5, dd = cv & 31;
            int w = row >> 6, n = row & 63;
            vt[(((size_t)w * 8 + hd) * 32 + dd) * 64 + n] = f2b(val);
          }
        } else {
          int w = row >> 6, n = row & 63;
          int b = w >> 10, hb = (w >> 5) & 31, wbk = w & 31;
          int hh = (hb * 8 + (n >> 3) + SHIFT_) & 255;
          int ww = (wbk * 8 + (n & 7) + SHIFT_) & 255;
          float res = b2f(qin[(size_t)row * 256 + col]);
          float sc  = xsrc[((((size_t)(b * 2)) * 256 + hh) * 256 + ww) * 256 + col];
          outf[(((size_t)b * 256 + hh) * 256 + ww) * 256 + col] = val + res + sc;
        }
      }
    }
}

// ---------------- kernel 3: per (window, head) attention --------------------
__global__ __launch_bounds__(64) void attn_k(
    const unsigned short* __restrict__ q, const unsigned short* __restrict__ k,
    const unsigned short* __restrict__ vt, const float* __restrict__ mask,
    const float* __restrict__ bias_table, unsigned short* __restrict__ aout){
  __shared__ unsigned short sQ[64][40];
  __shared__ unsigned short sK[64][40];
  __shared__ unsigned short sVT[32][72];
  __shared__ unsigned short sP[64][72];
  __shared__ float sBias[225];
  int bid = blockIdx.x;
  int w = bid >> 3, hd = bid & 7;
  int lane = threadIdx.x;
  int llo = lane & 15, lhi = lane >> 4;
  for (int i = lane; i < 225; i += 64) sBias[i] = bias_table[i * 8 + hd];
  {
    const unsigned short* qp = q + ((size_t)w * 64 + lane) * 256 + hd * 32;
    const unsigned short* kp = k + ((size_t)w * 64 + lane) * 256 + hd * 32;
    #pragma unroll
    for (int c2 = 0; c2 < 4; c2++){
      *(bh8*)&sQ[lane][c2 * 8] = *(const bh8*)(qp + c2 * 8);
      *(bh8*)&sK[lane][c2 * 8] = *(const bh8*)(kp + c2 * 8);
    }
    const unsigned short* vp = vt + (((size_t)w * 8 + hd) * 32 + (lane >> 1)) * 64 + (lane & 1) * 32;
    #pragma unroll
    for (int c2 = 0; c2 < 4; c2++)
      *(bh8*)&sVT[lane >> 1][(lane & 1) * 32 + c2 * 8] = *(const bh8*)(vp + c2 * 8);
  }
  __syncthreads();
  const f4 FZ = {0.f, 0.f, 0.f, 0.f};
  f4 acc[4][4];
  {
    bh8 a[4], b[4];
    #pragma unroll
    for (int mi = 0; mi < 4; mi++) a[mi] = *(const bh8*)&sQ[mi * 16 + llo][lhi * 8];
    #pragma unroll
    for (int nj = 0; nj < 4; nj++) b[nj] = *(const bh8*)&sK[nj * 16 + llo][lhi * 8];
    #pragma unroll
    for (int mi = 0; mi < 4; mi++)
      #pragma unroll
      for (int nj = 0; nj < 4; nj++)
        acc[mi][nj] = mfma16(a[mi], b[nj], FZ);
  }
  const float* mrow = mask + (size_t)(w & 1023) * 4096;
  #pragma unroll
  for (int mi = 0; mi < 4; mi++){
    #pragma unroll
    for (int r = 0; r < 4; r++){
      int rr = mi * 16 + lhi * 4 + r;
      int yi = rr >> 3, xi = rr & 7;
      float sv[4]; float mx = -1e30f;
      #pragma unroll
      for (int nj = 0; nj < 4; nj++){
        int cc = nj * 16 + llo;
        int idx = (yi - (cc >> 3) + 7) * 15 + (xi - (cc & 7) + 7);
        sv[nj] = acc[mi][nj][r] + sBias[idx] + mrow[rr * 64 + cc];
        mx = fmaxf(mx, sv[nj]);
      }
      #pragma unroll
      for (int off = 1; off < 16; off <<= 1) mx = fmaxf(mx, __shfl_xor(mx, off));
      float sum = 0.f;
      #pragma unroll
      for (int nj = 0; nj < 4; nj++){ sv[nj] = __expf(sv[nj] - mx); sum += sv[nj]; }
      #pragma unroll
      for (int off = 1; off < 16; off <<= 1) sum += __shfl_xor(sum, off);
      float inv = __builtin_amdgcn_rcpf(sum);
      #pragma unroll
      for (int nj = 0; nj < 4; nj++) sP[rr][nj * 16 + llo] = f2b(sv[nj] * inv);
    }
  }
  __syncthreads();
  f4 o[4][2];
  for (int mi = 0; mi < 4; mi++) for (int dj = 0; dj < 2; dj++) o[mi][dj] = FZ;
  #pragma unroll
  for (int ks = 0; ks < 2; ks++){
    bh8 pa[4], vb[2];
    #pragma unroll
    for (int mi = 0; mi < 4; mi++) pa[mi] = *(const bh8*)&sP[mi * 16 + llo][ks * 32 + lhi * 8];
    #pragma unroll
    for (int dj = 0; dj < 2; dj++) vb[dj] = *(const bh8*)&sVT[dj * 16 + llo][ks * 32 + lhi * 8];
    #pragma unroll
    for (int mi = 0; mi < 4; mi++)
      #pragma unroll
      for (int dj = 0; dj < 2; dj++)
        o[mi][dj] = mfma16(pa[mi], vb[dj], o[mi][dj]);
  }
  #pragma unroll
  for (int mi = 0; mi < 4; mi++)
    for (int dj = 0; dj < 2; dj++)
      for (int r = 0; r < 4; r++){
        int rr = mi * 16 + lhi * 4 + r, dd = dj * 16 + llo;
        aout[((size_t)w * 64 + rr) * 256 + hd * 32 + dd] = f2b(o[mi][dj][r]);
      }
}

// ---------------- kernel 4: LN2 -> bf16 xn (row-major) ----------------------
__global__ __launch_bounds__(256) void ln2_k(
    const float* __restrict__ x1, const float* __restrict__ g2,
    const float* __restrict__ b2, unsigned short* __restrict__ xn){
  int rid  = blockIdx.x * 4 + (threadIdx.x >> 6);   // 0..131071
  int lane = threadIdx.x & 63;
  const float* xr = x1 + (size_t)rid * 256;
  float4 v = *(const float4*)(xr + lane * 4);
  float s  = v.x + v.y + v.z + v.w;
  float ss = v.x * v.x + v.y * v.y + v.z * v.z + v.w * v.w;
  #pragma unroll
  for (int off = 1; off < 64; off <<= 1){ s += __shfl_xor(s, off); ss += __shfl_xor(ss, off); }
  float m    = s * (1.f / 256.f);
  float rstd = rsqrtf(ss * (1.f / 256.f) - m * m + 1e-5f);
  int c = lane * 4;
  float4 g  = *(const float4*)(g2 + c);
  float4 bb = *(const float4*)(b2 + c);
  sh4 o;
  o.x = (short)f2b((v.x - m) * rstd * g.x + bb.x);
  o.y = (short)f2b((v.y - m) * rstd * g.y + bb.y);
  o.z = (short)f2b((v.z - m) * rstd * g.z + bb.z);
  o.w = (short)f2b((v.w - m) * rstd * g.w + bb.w);
  *(sh4*)(xn + (size_t)rid * 256 + c) = o;
}

// ---------------- kernel 5: m97-template GEMM for the MLP -------------------
// 128x128 tile, BK=64, single-buffer LDS, global_load_lds width-16 staging
// (shared by all 4 waves), 2 barriers per K-step, 32 MFMA/wave/K-step.
// EPI 0: gelu -> bf16 (operand-swapped MFMA so lane packs 4 consecutive cols)
// EPI 1: outf[row*256+col] += acc (+ bias if BIASF)
template<int KSTEPS, int EPI, int BIASF>
__global__ __launch_bounds__(256, 3) void mlp_gemm(
    const unsigned short* __restrict__ A, int lda,
    const unsigned short* __restrict__ Bw, int ldb,
    const float* __restrict__ bias,
    unsigned short* __restrict__ outb, int ldo,
    float* __restrict__ outf){
  __shared__ unsigned short sA[128][64];
  __shared__ unsigned short sB[128][64];
  int n0 = blockIdx.x * 128, m0 = blockIdx.y * 128;
  int tid = threadIdx.x, lane = tid & 63, wid = tid >> 6;
  int wm = wid >> 1, wn = wid & 1;
  int llo = lane & 15, lhi = lane >> 4;
  int lr = lane >> 3, lc = (lane & 7) * 8;
  const f4 FZ = {0.f, 0.f, 0.f, 0.f};
  f4 acc[4][4];
  for (int i = 0; i < 4; i++) for (int j = 0; j < 4; j++) acc[i][j] = FZ;

  for (int t = 0; t < KSTEPS; t++){
    int k0 = t * 64;
    #pragma unroll
    for (int c = 0; c < 4; c++){
      int rr = wid * 32 + c * 8 + lr;
      __builtin_amdgcn_global_load_lds(
        (const __attribute__((address_space(1))) unsigned int*)(A + (size_t)(m0 + rr) * lda + k0 + lc),
        (__attribute__((address_space(3))) unsigned int*)&sA[wid * 32 + c * 8][0], 16, 0, 0);
      __builtin_amdgcn_global_load_lds(
        (const __attribute__((address_space(1))) unsigned int*)(Bw + (size_t)(n0 + rr) * ldb + k0 + lc),
        (__attribute__((address_space(3))) unsigned int*)&sB[wid * 32 + c * 8][0], 16, 0, 0);
    }
    __syncthreads();
    #pragma unroll
    for (int ks = 0; ks < 2; ks++){
      bh8 a[4], b[4];
      #pragma unroll
      for (int mi = 0; mi < 4; mi++) a[mi] = *(const bh8*)&sA[wm * 64 + mi * 16 + llo][ks * 32 + lhi * 8];
      #pragma unroll
      for (int nj = 0; nj < 4; nj++) b[nj] = *(const bh8*)&sB[wn * 64 + nj * 16 + llo][ks * 32 + lhi * 8];
      #pragma unroll
      for (int mi = 0; mi < 4; mi++)
        #pragma unroll
        for (int nj = 0; nj < 4; nj++){
          if (EPI == 0) acc[mi][nj] = mfma16(b[nj], a[mi], acc[mi][nj]);   // swapped
          else          acc[mi][nj] = mfma16(a[mi], b[nj], acc[mi][nj]);
        }
    }
    __syncthreads();
  }
  if (EPI == 0){
    // lane holds: out-row (from a, 2nd op) = m0+wm*64+mi*16+llo;
    //             out-col (from b, 1st op) = n0+wn*64+nj*16+lhi*4+r
    #pragma unroll
    for (int nj = 0; nj < 4; nj++){
      int cb = n0 + wn * 64 + nj * 16 + lhi * 4;
      float4 bv = *(const float4*)(bias + cb);
      #pragma unroll
      for (int mi = 0; mi < 4; mi++){
        int row = m0 + wm * 64 + mi * 16 + llo;
        float g0 = gelu_f(acc[mi][nj][0] + bv.x);
        float g1 = gelu_f(acc[mi][nj][1] + bv.y);
        float g2 = gelu_f(acc[mi][nj][2] + bv.z);
        float g3 = gelu_f(acc[mi][nj][3] + bv.w);
        uint2 p;
        p.x = cvt_pk_bf16(g0, g1);
        p.y = cvt_pk_bf16(g2, g3);
        *(uint2*)(outb + (size_t)row * ldo + cb) = p;
      }
    }
  } else {
    #pragma unroll
    for (int mi = 0; mi < 4; mi++)
      #pragma unroll
      for (int nj = 0; nj < 4; nj++){
        int col = n0 + wn * 64 + nj * 16 + llo;
        float bv = BIASF ? bias[col] : 0.f;
        #pragma unroll
        for (int r = 0; r < 4; r++){
          int row = m0 + wm * 64 + mi * 16 + lhi * 4 + r;
          outf[(size_t)row * 256 + col] += acc[mi][nj][r] + bv;
        }
      }
  }
}

extern "C" void kernel_launch(void* const* d_in, const int* in_sizes, int n_in,
                              void* d_out, int out_size, void* d_ws, size_t ws_size,
                              hipStream_t stream){
  const float* x          = (const float*)d_in[0];
  const float* mask       = (const float*)d_in[1];
  const float* g1         = (const float*)d_in[2];
  const float* b1         = (const float*)d_in[3];
  const float* qw         = (const float*)d_in[4];
  const float* qb         = (const float*)d_in[5];
  const float* kvw        = (const float*)d_in[6];
  const float* kvb        = (const float*)d_in[7];
  const float* pw         = (const float*)d_in[8];
  const float* pb         = (const float*)d_in[9];
  const float* bias_table = (const float*)d_in[10];
  const float* g2         = (const float*)d_in[11];
  const float* b2         = (const float*)d_in[12];
  const float* w1         = (const float*)d_in[13];
  const float* bi1        = (const float*)d_in[14];
  const float* w2         = (const float*)d_in[15];
  const float* bi2        = (const float*)d_in[16];
  float* out = (float*)d_out;
  char* ws = (char*)d_ws;
  const long long MB = 1048576LL;
  // layout (max offset 321.5MB, same budget as previous rounds):
  // wb @0(1.5MB) | q_in @1.5 | kv_in/aoutb @65.5 | qbuf @129.5 | kbuf @193.5
  // | vtb @257.5..321.5.  MLP phase reuse: xn @257.5 (vtb), H @1.5..135.5.
  unsigned short* wb    = (unsigned short*)(ws);
  unsigned short* q_in  = (unsigned short*)(ws + (long long)(1.5 * MB));
  unsigned short* kv_in = (unsigned short*)(ws + (long long)(65.5 * MB));
  unsigned short* qbuf  = (unsigned short*)(ws + (long long)(129.5 * MB));
  unsigned short* kbuf  = (unsigned short*)(ws + (long long)(193.5 * MB));
  unsigned short* vtb   = (unsigned short*)(ws + (long long)(257.5 * MB));
  unsigned short* aoutb = kv_in;      // kv_in dead after kv GEMM -> alias
  unsigned short* xn    = vtb;        // vtb dead after attn_k -> alias
  unsigned short* Hh    = q_in;       // q_in/kv_in dead after gemm<2> -> alias (134MB)

  prep_w<<<3072, 256, 0, stream>>>(qw, kvw, pw, w1, w2, wb);
  ln1_win<<<65536, 256, 0, stream>>>(x, g1, b1, q_in, kv_in);
  gemm_bt<0><<<dim3(1024, 2), 256, 0, stream>>>(q_in, wb, qb, 0.17677669529663687f,
                                                qbuf, nullptr, nullptr, nullptr, nullptr);
  gemm_bt<1><<<dim3(1024, 4), 256, 0, stream>>>(kv_in, wb + 65536, kvb, 1.0f,
                                                kbuf, vtb, nullptr, nullptr, nullptr);
  attn_k<<<16384, 64, 0, stream>>>(qbuf, kbuf, vtb, mask, bias_table, aoutb);
  gemm_bt<2><<<dim3(1024, 2), 256, 0, stream>>>(aoutb, wb + 196608, pb, 1.0f,
                                                nullptr, nullptr, out, q_in, x);
  ln2_k<<<32768, 256, 0, stream>>>(out, g2, b2, xn);
  const unsigned short* w1b = wb + 262144;
  const unsigned short* w2b = wb + 524288;
  // hidden slice a: [0,512)
  mlp_gemm<4, 0, 0><<<dim3(4, 1024), 256, 0, stream>>>(xn, 256, w1b, 256,
                                                       bi1, Hh, 512, nullptr);
  mlp_gemm<8, 1, 1><<<dim3(2, 1024), 256, 0, stream>>>(Hh, 512, w2b, 1024,
                                                       bi2, nullptr, 0, out);
  // hidden slice b: [512,1024)
  mlp_gemm<4, 0, 0><<<dim3(4, 1024), 256, 0, stream>>>(xn, 256, w1b + 512 * 256, 256,
                                                       bi1 + 512, Hh, 512, nullptr);
  mlp_gemm<8, 1, 0><<<dim3(2, 1024), 256, 0, stream>>>(Hh, 512, w2b + 512, 1024,
                                                       nullptr, nullptr, 0, out);
}

// Round 9
// 887.759 us; speedup vs baseline: 1.2158x; 1.0898x over previous
//
#include <hip/hip_runtime.h>
#include <hip/hip_bf16.h>
#include <math.h>

#define SHIFT_ 4

typedef __attribute__((ext_vector_type(8))) short bh8;
typedef __attribute__((ext_vector_type(4))) short sh4;
typedef __attribute__((ext_vector_type(4))) float f4;
typedef __attribute__((ext_vector_type(8))) __bf16 bf8t;

static __device__ __forceinline__ f4 mfma16(bh8 a, bh8 b, f4 c){
  return __builtin_amdgcn_mfma_f32_16x16x32_bf16(
    __builtin_bit_cast(bf8t, a), __builtin_bit_cast(bf8t, b), c, 0, 0, 0);
}
static __device__ __forceinline__ unsigned short f2b(float f){
  unsigned u = __builtin_bit_cast(unsigned, f);
  u += 0x7fffu + ((u >> 16) & 1u);
  return (unsigned short)(u >> 16);
}
static __device__ __forceinline__ float b2f(unsigned short h){
  return __builtin_bit_cast(float, ((unsigned)h) << 16);
}
static __device__ __forceinline__ unsigned cvt_pk_bf16(float lo, float hi){
  unsigned r;
  asm("v_cvt_pk_bf16_f32 %0, %1, %2" : "=v"(r) : "v"(lo), "v"(hi));
  return r;
}
static __device__ __forceinline__ float gelu_f(float hv){
  float u = hv * (1.5957691216f + 0.0713548162f * hv * hv);
  return hv * __builtin_amdgcn_rcpf(1.f + __expf(-u));
}

// ---------------- kernel 0: weights f32 -> bf16 (qw pre-scaled by d^-0.5) ---
__global__ __launch_bounds__(256) void prep_w(
    const float* __restrict__ qw, const float* __restrict__ kvw,
    const float* __restrict__ pw, const float* __restrict__ w1,
    const float* __restrict__ w2, unsigned short* __restrict__ wb){
  int i = blockIdx.x * 256 + threadIdx.x;   // 786432 total
  float v;
  if      (i < 65536)  v = qw[i] * 0.17677669529663687f;
  else if (i < 196608) v = kvw[i - 65536];
  else if (i < 262144) v = pw[i - 196608];
  else if (i < 524288) v = w1[i - 262144];
  else                 v = w2[i - 524288];
  wb[i] = f2b(v);
}

// ---------------- kernel 1: LN1 + roll(-4,-4) + window partition ------------
__global__ __launch_bounds__(256) void ln1_win(
    const float* __restrict__ x, const float* __restrict__ g1,
    const float* __restrict__ b1,
    unsigned short* __restrict__ q_in, unsigned short* __restrict__ kv_in){
  int rid  = blockIdx.x * 4 + (threadIdx.x >> 6);   // 0..262143
  int lane = threadIdx.x & 63;
  int d    = rid >> 17;
  int rem  = rid & 131071;          // w*64 + n
  int w = rem >> 6, n = rem & 63;
  int b = w >> 10, hb = (w >> 5) & 31, wbk = w & 31;
  int sh = (hb * 8 + (n >> 3) + SHIFT_) & 255;
  int sw = (wbk * 8 + (n & 7) + SHIFT_) & 255;
  const float* src = x + ((((size_t)(b * 2 + d)) * 256 + sh) * 256 + sw) * 256;
  float4 v = *(const float4*)(src + lane * 4);
  float s  = v.x + v.y + v.z + v.w;
  float ss = v.x * v.x + v.y * v.y + v.z * v.z + v.w * v.w;
  #pragma unroll
  for (int off = 1; off < 64; off <<= 1){ s += __shfl_xor(s, off); ss += __shfl_xor(ss, off); }
  float m    = s * (1.f / 256.f);
  float rstd = rsqrtf(ss * (1.f / 256.f) - m * m + 1e-5f);
  int c = lane * 4;
  float4 g  = *(const float4*)(g1 + c);
  float4 bb = *(const float4*)(b1 + c);
  sh4 o;
  o.x = (short)f2b((v.x - m) * rstd * g.x + bb.x);
  o.y = (short)f2b((v.y - m) * rstd * g.y + bb.y);
  o.z = (short)f2b((v.z - m) * rstd * g.z + bb.z);
  o.w = (short)f2b((v.w - m) * rstd * g.w + bb.w);
  unsigned short* dst = (d == 0 ? q_in : kv_in) + (size_t)rem * 256 + c;
  *(sh4*)dst = o;
}

// ---------------- QKV/P GEMM, m97-style: 512 thr, block 128 x (NT*256) ------
// 8 waves 2m x 4n (wave-tile 64x64), global_load_lds staging, K-loop 4x64.
// n-tile loop keeps A L2-resident for NT=2 (kv). Epilogues as before.
template<int MODE, int NT>
__global__ __launch_bounds__(512, 4) void gemm_bt(
    const unsigned short* __restrict__ A, const unsigned short* __restrict__ Wt,
    const float* __restrict__ bias, float bias_scale,
    unsigned short* __restrict__ outb, unsigned short* __restrict__ vt,
    float* __restrict__ outf, const unsigned short* __restrict__ qin,
    const float* __restrict__ xsrc){
  __shared__ unsigned short sA[128][64];
  __shared__ unsigned short sB[256][64];
  int m0 = blockIdx.x * 128;
  int tid = threadIdx.x, lane = tid & 63, wid = tid >> 6;   // 8 waves
  int wm = wid >> 2, wn = wid & 3;
  int llo = lane & 15, lhi = lane >> 4;
  int lr = lane >> 3, lc = (lane & 7) * 8;
  const f4 FZ = {0.f, 0.f, 0.f, 0.f};
  for (int nt = 0; nt < NT; nt++){
    f4 acc[4][4];
    for (int i = 0; i < 4; i++) for (int j = 0; j < 4; j++) acc[i][j] = FZ;
    for (int t = 0; t < 4; t++){
      int k0 = t * 64;
      #pragma unroll
      for (int c = 0; c < 2; c++){
        int rr = wid * 16 + c * 8;
        __builtin_amdgcn_global_load_lds(
          (const __attribute__((address_space(1))) unsigned int*)(A + (size_t)(m0 + rr + lr) * 256 + k0 + lc),
          (__attribute__((address_space(3))) unsigned int*)&sA[rr][0], 16, 0, 0);
      }
      #pragma unroll
      for (int c = 0; c < 4; c++){
        int rb = wid * 32 + c * 8;
        __builtin_amdgcn_global_load_lds(
          (const __attribute__((address_space(1))) unsigned int*)(Wt + (size_t)(nt * 256 + rb + lr) * 256 + k0 + lc),
          (__attribute__((address_space(3))) unsigned int*)&sB[rb][0], 16, 0, 0);
      }
      __syncthreads();
      #pragma unroll
      for (int ks = 0; ks < 2; ks++){
        bh8 a[4], b[4];
        #pragma unroll
        for (int mi = 0; mi < 4; mi++) a[mi] = *(const bh8*)&sA[wm * 64 + mi * 16 + llo][ks * 32 + lhi * 8];
        #pragma unroll
        for (int nj = 0; nj < 4; nj++) b[nj] = *(const bh8*)&sB[wn * 64 + nj * 16 + llo][ks * 32 + lhi * 8];
        #pragma unroll
        for (int mi = 0; mi < 4; mi++)
          #pragma unroll
          for (int nj = 0; nj < 4; nj++)
            acc[mi][nj] = mfma16(a[mi], b[nj], acc[mi][nj]);
      }
      __syncthreads();
    }
    #pragma unroll
    for (int mi = 0; mi < 4; mi++)
      #pragma unroll
      for (int nj = 0; nj < 4; nj++){
        int col = nt * 256 + wn * 64 + nj * 16 + llo;
        float bv = bias[col] * bias_scale;
        #pragma unroll
        for (int r = 0; r < 4; r++){
          int row = m0 + wm * 64 + mi * 16 + lhi * 4 + r;
          float val = acc[mi][nj][r] + bv;
          if (MODE == 0){
            outb[(size_t)row * 256 + col] = f2b(val);
          } else if (MODE == 1){
            if (col < 256) outb[(size_t)row * 256 + col] = f2b(val);
            else {
              int cv = col - 256, hd = cv >> 5, dd = cv & 31;
              int w = row >> 6, n = row & 63;
              vt[(((size_t)w * 8 + hd) * 32 + dd) * 64 + n] = f2b(val);
            }
          } else {
            int w = row >> 6, n = row & 63;
            int b = w >> 10, hb = (w >> 5) & 31, wbk = w & 31;
            int hh = (hb * 8 + (n >> 3) + SHIFT_) & 255;
            int ww = (wbk * 8 + (n & 7) + SHIFT_) & 255;
            float res = b2f(qin[(size_t)row * 256 + col]);
            float sc  = xsrc[((((size_t)(b * 2)) * 256 + hh) * 256 + ww) * 256 + col];
            outf[(((size_t)b * 256 + hh) * 256 + ww) * 256 + col] = val + res + sc;
          }
        }
      }
  }
}

// ---------------- kernel 3: per (window, head) attention --------------------
__global__ __launch_bounds__(64) void attn_k(
    const unsigned short* __restrict__ q, const unsigned short* __restrict__ k,
    const unsigned short* __restrict__ vt, const float* __restrict__ mask,
    const float* __restrict__ bias_table, unsigned short* __restrict__ aout){
  __shared__ unsigned short sQ[64][40];
  __shared__ unsigned short sK[64][40];
  __shared__ unsigned short sVT[32][72];
  __shared__ unsigned short sP[64][72];
  __shared__ float sBias[225];
  int bid = blockIdx.x;
  int w = bid >> 3, hd = bid & 7;
  int lane = threadIdx.x;
  int llo = lane & 15, lhi = lane >> 4;
  for (int i = lane; i < 225; i += 64) sBias[i] = bias_table[i * 8 + hd];
  {
    const unsigned short* qp = q + ((size_t)w * 64 + lane) * 256 + hd * 32;
    const unsigned short* kp = k + ((size_t)w * 64 + lane) * 256 + hd * 32;
    #pragma unroll
    for (int c2 = 0; c2 < 4; c2++){
      *(bh8*)&sQ[lane][c2 * 8] = *(const bh8*)(qp + c2 * 8);
      *(bh8*)&sK[lane][c2 * 8] = *(const bh8*)(kp + c2 * 8);
    }
    const unsigned short* vp = vt + (((size_t)w * 8 + hd) * 32 + (lane >> 1)) * 64 + (lane & 1) * 32;
    #pragma unroll
    for (int c2 = 0; c2 < 4; c2++)
      *(bh8*)&sVT[lane >> 1][(lane & 1) * 32 + c2 * 8] = *(const bh8*)(vp + c2 * 8);
  }
  __syncthreads();
  const f4 FZ = {0.f, 0.f, 0.f, 0.f};
  f4 acc[4][4];
  {
    bh8 a[4], b[4];
    #pragma unroll
    for (int mi = 0; mi < 4; mi++) a[mi] = *(const bh8*)&sQ[mi * 16 + llo][lhi * 8];
    #pragma unroll
    for (int nj = 0; nj < 4; nj++) b[nj] = *(const bh8*)&sK[nj * 16 + llo][lhi * 8];
    #pragma unroll
    for (int mi = 0; mi < 4; mi++)
      #pragma unroll
      for (int nj = 0; nj < 4; nj++)
        acc[mi][nj] = mfma16(a[mi], b[nj], FZ);
  }
  const float* mrow = mask + (size_t)(w & 1023) * 4096;
  #pragma unroll
  for (int mi = 0; mi < 4; mi++){
    #pragma unroll
    for (int r = 0; r < 4; r++){
      int rr = mi * 16 + lhi * 4 + r;
      int yi = rr >> 3, xi = rr & 7;
      float sv[4]; float mx = -1e30f;
      #pragma unroll
      for (int nj = 0; nj < 4; nj++){
        int cc = nj * 16 + llo;
        int idx = (yi - (cc >> 3) + 7) * 15 + (xi - (cc & 7) + 7);
        sv[nj] = acc[mi][nj][r] + sBias[idx] + mrow[rr * 64 + cc];
        mx = fmaxf(mx, sv[nj]);
      }
      #pragma unroll
      for (int off = 1; off < 16; off <<= 1) mx = fmaxf(mx, __shfl_xor(mx, off));
      float sum = 0.f;
      #pragma unroll
      for (int nj = 0; nj < 4; nj++){ sv[nj] = __expf(sv[nj] - mx); sum += sv[nj]; }
      #pragma unroll
      for (int off = 1; off < 16; off <<= 1) sum += __shfl_xor(sum, off);
      float inv = __builtin_amdgcn_rcpf(sum);
      #pragma unroll
      for (int nj = 0; nj < 4; nj++) sP[rr][nj * 16 + llo] = f2b(sv[nj] * inv);
    }
  }
  __syncthreads();
  f4 o[4][2];
  for (int mi = 0; mi < 4; mi++) for (int dj = 0; dj < 2; dj++) o[mi][dj] = FZ;
  #pragma unroll
  for (int ks = 0; ks < 2; ks++){
    bh8 pa[4], vb[2];
    #pragma unroll
    for (int mi = 0; mi < 4; mi++) pa[mi] = *(const bh8*)&sP[mi * 16 + llo][ks * 32 + lhi * 8];
    #pragma unroll
    for (int dj = 0; dj < 2; dj++) vb[dj] = *(const bh8*)&sVT[dj * 16 + llo][ks * 32 + lhi * 8];
    #pragma unroll
    for (int mi = 0; mi < 4; mi++)
      #pragma unroll
      for (int dj = 0; dj < 2; dj++)
        o[mi][dj] = mfma16(pa[mi], vb[dj], o[mi][dj]);
  }
  #pragma unroll
  for (int mi = 0; mi < 4; mi++)
    for (int dj = 0; dj < 2; dj++)
      for (int r = 0; r < 4; r++){
        int rr = mi * 16 + lhi * 4 + r, dd = dj * 16 + llo;
        aout[((size_t)w * 64 + rr) * 256 + hd * 32 + dd] = f2b(o[mi][dj][r]);
      }
}

// ---------------- kernel 4: LN2 -> bf16 xn (row-major) ----------------------
__global__ __launch_bounds__(256) void ln2_k(
    const float* __restrict__ x1, const float* __restrict__ g2,
    const float* __restrict__ b2, unsigned short* __restrict__ xn){
  int rid  = blockIdx.x * 4 + (threadIdx.x >> 6);   // 0..131071
  int lane = threadIdx.x & 63;
  const float* xr = x1 + (size_t)rid * 256;
  float4 v = *(const float4*)(xr + lane * 4);
  float s  = v.x + v.y + v.z + v.w;
  float ss = v.x * v.x + v.y * v.y + v.z * v.z + v.w * v.w;
  #pragma unroll
  for (int off = 1; off < 64; off <<= 1){ s += __shfl_xor(s, off); ss += __shfl_xor(ss, off); }
  float m    = s * (1.f / 256.f);
  float rstd = rsqrtf(ss * (1.f / 256.f) - m * m + 1e-5f);
  int c = lane * 4;
  float4 g  = *(const float4*)(g2 + c);
  float4 bb = *(const float4*)(b2 + c);
  sh4 o;
  o.x = (short)f2b((v.x - m) * rstd * g.x + bb.x);
  o.y = (short)f2b((v.y - m) * rstd * g.y + bb.y);
  o.z = (short)f2b((v.z - m) * rstd * g.z + bb.z);
  o.w = (short)f2b((v.w - m) * rstd * g.w + bb.w);
  *(sh4*)(xn + (size_t)rid * 256 + c) = o;
}

// ---------------- kernel 5: m97-template GEMM for the MLP -------------------
template<int KSTEPS, int EPI, int BIASF>
__global__ __launch_bounds__(256, 3) void mlp_gemm(
    const unsigned short* __restrict__ A, int lda,
    const unsigned short* __restrict__ Bw, int ldb,
    const float* __restrict__ bias,
    unsigned short* __restrict__ outb, int ldo,
    float* __restrict__ outf){
  __shared__ unsigned short sA[128][64];
  __shared__ unsigned short sB[128][64];
  int n0 = blockIdx.x * 128, m0 = blockIdx.y * 128;
  int tid = threadIdx.x, lane = tid & 63, wid = tid >> 6;
  int wm = wid >> 1, wn = wid & 1;
  int llo = lane & 15, lhi = lane >> 4;
  int lr = lane >> 3, lc = (lane & 7) * 8;
  const f4 FZ = {0.f, 0.f, 0.f, 0.f};
  f4 acc[4][4];
  for (int i = 0; i < 4; i++) for (int j = 0; j < 4; j++) acc[i][j] = FZ;

  for (int t = 0; t < KSTEPS; t++){
    int k0 = t * 64;
    #pragma unroll
    for (int c = 0; c < 4; c++){
      int rr = wid * 32 + c * 8 + lr;
      __builtin_amdgcn_global_load_lds(
        (const __attribute__((address_space(1))) unsigned int*)(A + (size_t)(m0 + rr) * lda + k0 + lc),
        (__attribute__((address_space(3))) unsigned int*)&sA[wid * 32 + c * 8][0], 16, 0, 0);
      __builtin_amdgcn_global_load_lds(
        (const __attribute__((address_space(1))) unsigned int*)(Bw + (size_t)(n0 + rr) * ldb + k0 + lc),
        (__attribute__((address_space(3))) unsigned int*)&sB[wid * 32 + c * 8][0], 16, 0, 0);
    }
    __syncthreads();
    #pragma unroll
    for (int ks = 0; ks < 2; ks++){
      bh8 a[4], b[4];
      #pragma unroll
      for (int mi = 0; mi < 4; mi++) a[mi] = *(const bh8*)&sA[wm * 64 + mi * 16 + llo][ks * 32 + lhi * 8];
      #pragma unroll
      for (int nj = 0; nj < 4; nj++) b[nj] = *(const bh8*)&sB[wn * 64 + nj * 16 + llo][ks * 32 + lhi * 8];
      #pragma unroll
      for (int mi = 0; mi < 4; mi++)
        #pragma unroll
        for (int nj = 0; nj < 4; nj++){
          if (EPI == 0) acc[mi][nj] = mfma16(b[nj], a[mi], acc[mi][nj]);   // swapped
          else          acc[mi][nj] = mfma16(a[mi], b[nj], acc[mi][nj]);
        }
    }
    __syncthreads();
  }
  if (EPI == 0){
    #pragma unroll
    for (int nj = 0; nj < 4; nj++){
      int cb = n0 + wn * 64 + nj * 16 + lhi * 4;
      float4 bv = *(const float4*)(bias + cb);
      #pragma unroll
      for (int mi = 0; mi < 4; mi++){
        int row = m0 + wm * 64 + mi * 16 + llo;
        float g0 = gelu_f(acc[mi][nj][0] + bv.x);
        float g1 = gelu_f(acc[mi][nj][1] + bv.y);
        float g2 = gelu_f(acc[mi][nj][2] + bv.z);
        float g3 = gelu_f(acc[mi][nj][3] + bv.w);
        uint2 p;
        p.x = cvt_pk_bf16(g0, g1);
        p.y = cvt_pk_bf16(g2, g3);
        *(uint2*)(outb + (size_t)row * ldo + cb) = p;
      }
    }
  } else {
    #pragma unroll
    for (int mi = 0; mi < 4; mi++)
      #pragma unroll
      for (int nj = 0; nj < 4; nj++){
        int col = n0 + wn * 64 + nj * 16 + llo;
        float bv = BIASF ? bias[col] : 0.f;
        #pragma unroll
        for (int r = 0; r < 4; r++){
          int row = m0 + wm * 64 + mi * 16 + lhi * 4 + r;
          outf[(size_t)row * 256 + col] += acc[mi][nj][r] + bv;
        }
      }
  }
}

extern "C" void kernel_launch(void* const* d_in, const int* in_sizes, int n_in,
                              void* d_out, int out_size, void* d_ws, size_t ws_size,
                              hipStream_t stream){
  const float* x          = (const float*)d_in[0];
  const float* mask       = (const float*)d_in[1];
  const float* g1         = (const float*)d_in[2];
  const float* b1         = (const float*)d_in[3];
  const float* qw         = (const float*)d_in[4];
  const float* qb         = (const float*)d_in[5];
  const float* kvw        = (const float*)d_in[6];
  const float* kvb        = (const float*)d_in[7];
  const float* pw         = (const float*)d_in[8];
  const float* pb         = (const float*)d_in[9];
  const float* bias_table = (const float*)d_in[10];
  const float* g2         = (const float*)d_in[11];
  const float* b2         = (const float*)d_in[12];
  const float* w1         = (const float*)d_in[13];
  const float* bi1        = (const float*)d_in[14];
  const float* w2         = (const float*)d_in[15];
  const float* bi2        = (const float*)d_in[16];
  float* out = (float*)d_out;
  char* ws = (char*)d_ws;
  const long long MB = 1048576LL;
  // wb @0(1.5MB) | q_in @1.5 | kv_in/aoutb @65.5 | qbuf @129.5 | kbuf @193.5
  // | vtb @257.5..321.5.  MLP phase: xn @257.5 (vtb), H @1.5..135.5 (dead bufs)
  unsigned short* wb    = (unsigned short*)(ws);
  unsigned short* q_in  = (unsigned short*)(ws + (long long)(1.5 * MB));
  unsigned short* kv_in = (unsigned short*)(ws + (long long)(65.5 * MB));
  unsigned short* qbuf  = (unsigned short*)(ws + (long long)(129.5 * MB));
  unsigned short* kbuf  = (unsigned short*)(ws + (long long)(193.5 * MB));
  unsigned short* vtb   = (unsigned short*)(ws + (long long)(257.5 * MB));
  unsigned short* aoutb = kv_in;      // kv_in dead after kv GEMM -> alias
  unsigned short* xn    = vtb;        // vtb dead after attn_k -> alias
  unsigned short* Hh    = q_in;       // dead after gemm<2> -> alias (134MB, half-M x 1024)

  prep_w<<<3072, 256, 0, stream>>>(qw, kvw, pw, w1, w2, wb);
  ln1_win<<<65536, 256, 0, stream>>>(x, g1, b1, q_in, kv_in);
  gemm_bt<0, 1><<<1024, 512, 0, stream>>>(q_in, wb, qb, 0.17677669529663687f,
                                          qbuf, nullptr, nullptr, nullptr, nullptr);
  gemm_bt<1, 2><<<1024, 512, 0, stream>>>(kv_in, wb + 65536, kvb, 1.0f,
                                          kbuf, vtb, nullptr, nullptr, nullptr);
  attn_k<<<16384, 64, 0, stream>>>(qbuf, kbuf, vtb, mask, bias_table, aoutb);
  gemm_bt<2, 1><<<1024, 512, 0, stream>>>(aoutb, wb + 196608, pb, 1.0f,
                                          nullptr, nullptr, out, q_in, x);
  ln2_k<<<32768, 256, 0, stream>>>(out, g2, b2, xn);
  const unsigned short* w1b = wb + 262144;
  const unsigned short* w2b = wb + 524288;
  // M-sliced MLP: per half, GEMM1 over full hidden then one += pass on out.
  for (int h = 0; h < 2; h++){
    const long long R = (long long)h * 65536;
    mlp_gemm<4, 0, 0><<<dim3(8, 512), 256, 0, stream>>>(xn + R * 256, 256, w1b, 256,
                                                        bi1, Hh, 1024, nullptr);
    mlp_gemm<16, 1, 1><<<dim3(2, 512), 256, 0, stream>>>(Hh, 1024, w2b, 1024,
                                                         bi2, nullptr, 0, out + R * 256);
  }
}

// Round 10
// 829.111 us; speedup vs baseline: 1.3018x; 1.0707x over previous
//
#include <hip/hip_runtime.h>
#include <hip/hip_bf16.h>
#include <math.h>

#define SHIFT_ 4

typedef __attribute__((ext_vector_type(8))) short bh8;
typedef __attribute__((ext_vector_type(4))) short sh4;
typedef __attribute__((ext_vector_type(4))) float f4;
typedef __attribute__((ext_vector_type(8))) __bf16 bf8t;

static __device__ __forceinline__ f4 mfma16(bh8 a, bh8 b, f4 c){
  return __builtin_amdgcn_mfma_f32_16x16x32_bf16(
    __builtin_bit_cast(bf8t, a), __builtin_bit_cast(bf8t, b), c, 0, 0, 0);
}
static __device__ __forceinline__ unsigned short f2b(float f){
  unsigned u = __builtin_bit_cast(unsigned, f);
  u += 0x7fffu + ((u >> 16) & 1u);
  return (unsigned short)(u >> 16);
}
static __device__ __forceinline__ float b2f(unsigned short h){
  return __builtin_bit_cast(float, ((unsigned)h) << 16);
}
static __device__ __forceinline__ unsigned cvt_pk_bf16(float lo, float hi){
  unsigned r;
  asm("v_cvt_pk_bf16_f32 %0, %1, %2" : "=v"(r) : "v"(lo), "v"(hi));
  return r;
}
static __device__ __forceinline__ float gelu_f(float hv){
  float u = hv * (1.5957691216f + 0.0713548162f * hv * hv);
  return hv * __builtin_amdgcn_rcpf(1.f + __expf(-u));
}

// ---------------- kernel 0: weights f32 -> bf16 (qw pre-scaled by d^-0.5) ---
__global__ __launch_bounds__(256) void prep_w(
    const float* __restrict__ qw, const float* __restrict__ kvw,
    const float* __restrict__ pw, const float* __restrict__ w1,
    const float* __restrict__ w2, unsigned short* __restrict__ wb){
  int i = blockIdx.x * 256 + threadIdx.x;   // 786432 total
  float v;
  if      (i < 65536)  v = qw[i] * 0.17677669529663687f;
  else if (i < 196608) v = kvw[i - 65536];
  else if (i < 262144) v = pw[i - 196608];
  else if (i < 524288) v = w1[i - 262144];
  else                 v = w2[i - 524288];
  wb[i] = f2b(v);
}

// ---------------- kernel 1: LN1 + roll(-4,-4) + window partition ------------
__global__ __launch_bounds__(256) void ln1_win(
    const float* __restrict__ x, const float* __restrict__ g1,
    const float* __restrict__ b1,
    unsigned short* __restrict__ q_in, unsigned short* __restrict__ kv_in){
  int rid  = blockIdx.x * 4 + (threadIdx.x >> 6);   // 0..262143
  int lane = threadIdx.x & 63;
  int d    = rid >> 17;
  int rem  = rid & 131071;          // w*64 + n
  int w = rem >> 6, n = rem & 63;
  int b = w >> 10, hb = (w >> 5) & 31, wbk = w & 31;
  int sh = (hb * 8 + (n >> 3) + SHIFT_) & 255;
  int sw = (wbk * 8 + (n & 7) + SHIFT_) & 255;
  const float* src = x + ((((size_t)(b * 2 + d)) * 256 + sh) * 256 + sw) * 256;
  float4 v = *(const float4*)(src + lane * 4);
  float s  = v.x + v.y + v.z + v.w;
  float ss = v.x * v.x + v.y * v.y + v.z * v.z + v.w * v.w;
  #pragma unroll
  for (int off = 1; off < 64; off <<= 1){ s += __shfl_xor(s, off); ss += __shfl_xor(ss, off); }
  float m    = s * (1.f / 256.f);
  float rstd = rsqrtf(ss * (1.f / 256.f) - m * m + 1e-5f);
  int c = lane * 4;
  float4 g  = *(const float4*)(g1 + c);
  float4 bb = *(const float4*)(b1 + c);
  sh4 o;
  o.x = (short)f2b((v.x - m) * rstd * g.x + bb.x);
  o.y = (short)f2b((v.y - m) * rstd * g.y + bb.y);
  o.z = (short)f2b((v.z - m) * rstd * g.z + bb.z);
  o.w = (short)f2b((v.w - m) * rstd * g.w + bb.w);
  unsigned short* dst = (d == 0 ? q_in : kv_in) + (size_t)rem * 256 + c;
  *(sh4*)dst = o;
}

// ---------------- QKV/P GEMM, 512 thr, block 128 x (NT*256) -----------------
// MODE 0/1: swapped-operand MFMA -> lane packs 4 consecutive cols -> uint2
// stores (full-line coalescing). MODE1 writes k and PLAIN v (no transpose).
// MODE 2: normal orientation, f32 epilogue with residual+unroll scatter.
template<int MODE, int NT>
__global__ __launch_bounds__(512, 4) void gemm_bt(
    const unsigned short* __restrict__ A, const unsigned short* __restrict__ Wt,
    const float* __restrict__ bias, float bias_scale,
    unsigned short* __restrict__ outb, unsigned short* __restrict__ vpl,
    float* __restrict__ outf, const unsigned short* __restrict__ qin,
    const float* __restrict__ xsrc){
  __shared__ unsigned short sA[128][64];
  __shared__ unsigned short sB[256][64];
  int m0 = blockIdx.x * 128;
  int tid = threadIdx.x, lane = tid & 63, wid = tid >> 6;   // 8 waves
  int wm = wid >> 2, wn = wid & 3;
  int llo = lane & 15, lhi = lane >> 4;
  int lr = lane >> 3, lc = (lane & 7) * 8;
  const f4 FZ = {0.f, 0.f, 0.f, 0.f};
  for (int nt = 0; nt < NT; nt++){
    f4 acc[4][4];
    for (int i = 0; i < 4; i++) for (int j = 0; j < 4; j++) acc[i][j] = FZ;
    for (int t = 0; t < 4; t++){
      int k0 = t * 64;
      #pragma unroll
      for (int c = 0; c < 2; c++){
        int rr = wid * 16 + c * 8;
        __builtin_amdgcn_global_load_lds(
          (const __attribute__((address_space(1))) unsigned int*)(A + (size_t)(m0 + rr + lr) * 256 + k0 + lc),
          (__attribute__((address_space(3))) unsigned int*)&sA[rr][0], 16, 0, 0);
      }
      #pragma unroll
      for (int c = 0; c < 4; c++){
        int rb = wid * 32 + c * 8;
        __builtin_amdgcn_global_load_lds(
          (const __attribute__((address_space(1))) unsigned int*)(Wt + (size_t)(nt * 256 + rb + lr) * 256 + k0 + lc),
          (__attribute__((address_space(3))) unsigned int*)&sB[rb][0], 16, 0, 0);
      }
      __syncthreads();
      #pragma unroll
      for (int ks = 0; ks < 2; ks++){
        bh8 a[4], b[4];
        #pragma unroll
        for (int mi = 0; mi < 4; mi++) a[mi] = *(const bh8*)&sA[wm * 64 + mi * 16 + llo][ks * 32 + lhi * 8];
        #pragma unroll
        for (int nj = 0; nj < 4; nj++) b[nj] = *(const bh8*)&sB[wn * 64 + nj * 16 + llo][ks * 32 + lhi * 8];
        #pragma unroll
        for (int mi = 0; mi < 4; mi++)
          #pragma unroll
          for (int nj = 0; nj < 4; nj++){
            if (MODE < 2) acc[mi][nj] = mfma16(b[nj], a[mi], acc[mi][nj]);   // swapped
            else          acc[mi][nj] = mfma16(a[mi], b[nj], acc[mi][nj]);
          }
      }
      __syncthreads();
    }
    if (MODE < 2){
      // lane: col = nt*256 + wn*64 + nj*16 + lhi*4 + r (4 consec), row = m0+wm*64+mi*16+llo
      #pragma unroll
      for (int nj = 0; nj < 4; nj++){
        int cb = wn * 64 + nj * 16 + lhi * 4;
        int col = nt * 256 + cb;
        float4 bv = *(const float4*)(bias + col);
        #pragma unroll
        for (int mi = 0; mi < 4; mi++){
          int row = m0 + wm * 64 + mi * 16 + llo;
          float f0 = acc[mi][nj][0] + bv.x * bias_scale;
          float f1 = acc[mi][nj][1] + bv.y * bias_scale;
          float f2 = acc[mi][nj][2] + bv.z * bias_scale;
          float f3 = acc[mi][nj][3] + bv.w * bias_scale;
          uint2 p;
          p.x = cvt_pk_bf16(f0, f1);
          p.y = cvt_pk_bf16(f2, f3);
          if (MODE == 0 || nt == 0) *(uint2*)(outb + (size_t)row * 256 + cb) = p;
          else                      *(uint2*)(vpl  + (size_t)row * 256 + cb) = p;
        }
      }
    } else {
      #pragma unroll
      for (int mi = 0; mi < 4; mi++)
        #pragma unroll
        for (int nj = 0; nj < 4; nj++){
          int col = wn * 64 + nj * 16 + llo;
          float bv = bias[col] * bias_scale;
          #pragma unroll
          for (int r = 0; r < 4; r++){
            int row = m0 + wm * 64 + mi * 16 + lhi * 4 + r;
            int w = row >> 6, n = row & 63;
            int b = w >> 10, hb = (w >> 5) & 31, wbk = w & 31;
            int hh = (hb * 8 + (n >> 3) + SHIFT_) & 255;
            int ww = (wbk * 8 + (n & 7) + SHIFT_) & 255;
            float res = b2f(qin[(size_t)row * 256 + col]);
            float sc  = xsrc[((((size_t)(b * 2)) * 256 + hh) * 256 + ww) * 256 + col];
            outf[(((size_t)b * 256 + hh) * 256 + ww) * 256 + col] = acc[mi][nj][r] + bv + res + sc;
          }
        }
    }
  }
}

// ---------------- kernel 3: per (window, head) attention --------------------
// V now plain row-major; transposed to sVT via LDS (cheap vs GEMM scatter).
__global__ __launch_bounds__(64) void attn_k(
    const unsigned short* __restrict__ q, const unsigned short* __restrict__ k,
    const unsigned short* __restrict__ v, const float* __restrict__ mask,
    const float* __restrict__ bias_table, unsigned short* __restrict__ aout){
  __shared__ unsigned short sQ[64][40];
  __shared__ unsigned short sK[64][40];
  __shared__ unsigned short sV[64][34];
  __shared__ unsigned short sVT[32][72];
  __shared__ unsigned short sP[64][72];
  __shared__ float sBias[225];
  int bid = blockIdx.x;
  int w = bid >> 3, hd = bid & 7;
  int lane = threadIdx.x;
  int llo = lane & 15, lhi = lane >> 4;
  for (int i = lane; i < 225; i += 64) sBias[i] = bias_table[i * 8 + hd];
  {
    const unsigned short* qp = q + ((size_t)w * 64 + lane) * 256 + hd * 32;
    const unsigned short* kp = k + ((size_t)w * 64 + lane) * 256 + hd * 32;
    const unsigned short* vp = v + ((size_t)w * 64 + lane) * 256 + hd * 32;
    #pragma unroll
    for (int c2 = 0; c2 < 4; c2++){
      *(bh8*)&sQ[lane][c2 * 8] = *(const bh8*)(qp + c2 * 8);
      *(bh8*)&sK[lane][c2 * 8] = *(const bh8*)(kp + c2 * 8);
      *(bh8*)&sV[lane][c2 * 8] = *(const bh8*)(vp + c2 * 8);
    }
  }
  __syncthreads();
  const f4 FZ = {0.f, 0.f, 0.f, 0.f};
  f4 acc[4][4];
  {
    bh8 a[4], b[4];
    #pragma unroll
    for (int mi = 0; mi < 4; mi++) a[mi] = *(const bh8*)&sQ[mi * 16 + llo][lhi * 8];
    #pragma unroll
    for (int nj = 0; nj < 4; nj++) b[nj] = *(const bh8*)&sK[nj * 16 + llo][lhi * 8];
    #pragma unroll
    for (int mi = 0; mi < 4; mi++)
      #pragma unroll
      for (int nj = 0; nj < 4; nj++)
        acc[mi][nj] = mfma16(a[mi], b[nj], FZ);
  }
  // transpose V into sVT: lane owns d = lane>>1, n-half = (lane&1)*32
  {
    int dv = lane >> 1, n0 = (lane & 1) * 32;
    #pragma unroll
    for (int i = 0; i < 32; i += 2){
      unsigned lo = sV[n0 + i][dv], hi = sV[n0 + i + 1][dv];
      *(unsigned*)&sVT[dv][n0 + i] = lo | (hi << 16);
    }
  }
  const float* mrow = mask + (size_t)(w & 1023) * 4096;
  #pragma unroll
  for (int mi = 0; mi < 4; mi++){
    #pragma unroll
    for (int r = 0; r < 4; r++){
      int rr = mi * 16 + lhi * 4 + r;
      int yi = rr >> 3, xi = rr & 7;
      float sv[4]; float mx = -1e30f;
      #pragma unroll
      for (int nj = 0; nj < 4; nj++){
        int cc = nj * 16 + llo;
        int idx = (yi - (cc >> 3) + 7) * 15 + (xi - (cc & 7) + 7);
        sv[nj] = acc[mi][nj][r] + sBias[idx] + mrow[rr * 64 + cc];
        mx = fmaxf(mx, sv[nj]);
      }
      #pragma unroll
      for (int off = 1; off < 16; off <<= 1) mx = fmaxf(mx, __shfl_xor(mx, off));
      float sum = 0.f;
      #pragma unroll
      for (int nj = 0; nj < 4; nj++){ sv[nj] = __expf(sv[nj] - mx); sum += sv[nj]; }
      #pragma unroll
      for (int off = 1; off < 16; off <<= 1) sum += __shfl_xor(sum, off);
      float inv = __builtin_amdgcn_rcpf(sum);
      #pragma unroll
      for (int nj = 0; nj < 4; nj++) sP[rr][nj * 16 + llo] = f2b(sv[nj] * inv);
    }
  }
  __syncthreads();
  f4 o[4][2];
  for (int mi = 0; mi < 4; mi++) for (int dj = 0; dj < 2; dj++) o[mi][dj] = FZ;
  #pragma unroll
  for (int ks = 0; ks < 2; ks++){
    bh8 pa[4], vb[2];
    #pragma unroll
    for (int mi = 0; mi < 4; mi++) pa[mi] = *(const bh8*)&sP[mi * 16 + llo][ks * 32 + lhi * 8];
    #pragma unroll
    for (int dj = 0; dj < 2; dj++) vb[dj] = *(const bh8*)&sVT[dj * 16 + llo][ks * 32 + lhi * 8];
    #pragma unroll
    for (int mi = 0; mi < 4; mi++)
      #pragma unroll
      for (int dj = 0; dj < 2; dj++)
        o[mi][dj] = mfma16(pa[mi], vb[dj], o[mi][dj]);
  }
  #pragma unroll
  for (int mi = 0; mi < 4; mi++)
    for (int dj = 0; dj < 2; dj++)
      for (int r = 0; r < 4; r++){
        int rr = mi * 16 + lhi * 4 + r, dd = dj * 16 + llo;
        aout[((size_t)w * 64 + rr) * 256 + hd * 32 + dd] = f2b(o[mi][dj][r]);
      }
}

// ---------------- kernel 4: LN2 -> bf16 xn (row-major) ----------------------
__global__ __launch_bounds__(256) void ln2_k(
    const float* __restrict__ x1, const float* __restrict__ g2,
    const float* __restrict__ b2, unsigned short* __restrict__ xn){
  int rid  = blockIdx.x * 4 + (threadIdx.x >> 6);   // 0..131071
  int lane = threadIdx.x & 63;
  const float* xr = x1 + (size_t)rid * 256;
  float4 v = *(const float4*)(xr + lane * 4);
  float s  = v.x + v.y + v.z + v.w;
  float ss = v.x * v.x + v.y * v.y + v.z * v.z + v.w * v.w;
  #pragma unroll
  for (int off = 1; off < 64; off <<= 1){ s += __shfl_xor(s, off); ss += __shfl_xor(ss, off); }
  float m    = s * (1.f / 256.f);
  float rstd = rsqrtf(ss * (1.f / 256.f) - m * m + 1e-5f);
  int c = lane * 4;
  float4 g  = *(const float4*)(g2 + c);
  float4 bb = *(const float4*)(b2 + c);
  sh4 o;
  o.x = (short)f2b((v.x - m) * rstd * g.x + bb.x);
  o.y = (short)f2b((v.y - m) * rstd * g.y + bb.y);
  o.z = (short)f2b((v.z - m) * rstd * g.z + bb.z);
  o.w = (short)f2b((v.w - m) * rstd * g.w + bb.w);
  *(sh4*)(xn + (size_t)rid * 256 + c) = o;
}

// ---------------- kernel 5: m97-template GEMM for the MLP -------------------
template<int KSTEPS, int EPI, int BIASF>
__global__ __launch_bounds__(256, 3) void mlp_gemm(
    const unsigned short* __restrict__ A, int lda,
    const unsigned short* __restrict__ Bw, int ldb,
    const float* __restrict__ bias,
    unsigned short* __restrict__ outb, int ldo,
    float* __restrict__ outf){
  __shared__ unsigned short sA[128][64];
  __shared__ unsigned short sB[128][64];
  int n0 = blockIdx.x * 128, m0 = blockIdx.y * 128;
  int tid = threadIdx.x, lane = tid & 63, wid = tid >> 6;
  int wm = wid >> 1, wn = wid & 1;
  int llo = lane & 15, lhi = lane >> 4;
  int lr = lane >> 3, lc = (lane & 7) * 8;
  const f4 FZ = {0.f, 0.f, 0.f, 0.f};
  f4 acc[4][4];
  for (int i = 0; i < 4; i++) for (int j = 0; j < 4; j++) acc[i][j] = FZ;

  for (int t = 0; t < KSTEPS; t++){
    int k0 = t * 64;
    #pragma unroll
    for (int c = 0; c < 4; c++){
      int rr = wid * 32 + c * 8 + lr;
      __builtin_amdgcn_global_load_lds(
        (const __attribute__((address_space(1))) unsigned int*)(A + (size_t)(m0 + rr) * lda + k0 + lc),
        (__attribute__((address_space(3))) unsigned int*)&sA[wid * 32 + c * 8][0], 16, 0, 0);
      __builtin_amdgcn_global_load_lds(
        (const __attribute__((address_space(1))) unsigned int*)(Bw + (size_t)(n0 + rr) * ldb + k0 + lc),
        (__attribute__((address_space(3))) unsigned int*)&sB[wid * 32 + c * 8][0], 16, 0, 0);
    }
    __syncthreads();
    #pragma unroll
    for (int ks = 0; ks < 2; ks++){
      bh8 a[4], b[4];
      #pragma unroll
      for (int mi = 0; mi < 4; mi++) a[mi] = *(const bh8*)&sA[wm * 64 + mi * 16 + llo][ks * 32 + lhi * 8];
      #pragma unroll
      for (int nj = 0; nj < 4; nj++) b[nj] = *(const bh8*)&sB[wn * 64 + nj * 16 + llo][ks * 32 + lhi * 8];
      #pragma unroll
      for (int mi = 0; mi < 4; mi++)
        #pragma unroll
        for (int nj = 0; nj < 4; nj++){
          if (EPI == 0) acc[mi][nj] = mfma16(b[nj], a[mi], acc[mi][nj]);   // swapped
          else          acc[mi][nj] = mfma16(a[mi], b[nj], acc[mi][nj]);
        }
    }
    __syncthreads();
  }
  if (EPI == 0){
    #pragma unroll
    for (int nj = 0; nj < 4; nj++){
      int cb = n0 + wn * 64 + nj * 16 + lhi * 4;
      float4 bv = *(const float4*)(bias + cb);
      #pragma unroll
      for (int mi = 0; mi < 4; mi++){
        int row = m0 + wm * 64 + mi * 16 + llo;
        float g0 = gelu_f(acc[mi][nj][0] + bv.x);
        float g1 = gelu_f(acc[mi][nj][1] + bv.y);
        float g2 = gelu_f(acc[mi][nj][2] + bv.z);
        float g3 = gelu_f(acc[mi][nj][3] + bv.w);
        uint2 p;
        p.x = cvt_pk_bf16(g0, g1);
        p.y = cvt_pk_bf16(g2, g3);
        *(uint2*)(outb + (size_t)row * ldo + cb) = p;
      }
    }
  } else {
    #pragma unroll
    for (int mi = 0; mi < 4; mi++)
      #pragma unroll
      for (int nj = 0; nj < 4; nj++){
        int col = n0 + wn * 64 + nj * 16 + llo;
        float bv = BIASF ? bias[col] : 0.f;
        #pragma unroll
        for (int r = 0; r < 4; r++){
          int row = m0 + wm * 64 + mi * 16 + lhi * 4 + r;
          outf[(size_t)row * 256 + col] += acc[mi][nj][r] + bv;
        }
      }
  }
}

extern "C" void kernel_launch(void* const* d_in, const int* in_sizes, int n_in,
                              void* d_out, int out_size, void* d_ws, size_t ws_size,
                              hipStream_t stream){
  const float* x          = (const float*)d_in[0];
  const float* mask       = (const float*)d_in[1];
  const float* g1         = (const float*)d_in[2];
  const float* b1         = (const float*)d_in[3];
  const float* qw         = (const float*)d_in[4];
  const float* qb         = (const float*)d_in[5];
  const float* kvw        = (const float*)d_in[6];
  const float* kvb        = (const float*)d_in[7];
  const float* pw         = (const float*)d_in[8];
  const float* pb         = (const float*)d_in[9];
  const float* bias_table = (const float*)d_in[10];
  const float* g2         = (const float*)d_in[11];
  const float* b2         = (const float*)d_in[12];
  const float* w1         = (const float*)d_in[13];
  const float* bi1        = (const float*)d_in[14];
  const float* w2         = (const float*)d_in[15];
  const float* bi2        = (const float*)d_in[16];
  float* out = (float*)d_out;
  char* ws = (char*)d_ws;
  const long long MB = 1048576LL;
  // wb @0(1.5MB) | q_in @1.5 | kv_in/aoutb @65.5 | qbuf @129.5 | kbuf @193.5
  // | vbuf @257.5..321.5.  MLP phase: xn @257.5 (vbuf), H @1.5..135.5
  unsigned short* wb    = (unsigned short*)(ws);
  unsigned short* q_in  = (unsigned short*)(ws + (long long)(1.5 * MB));
  unsigned short* kv_in = (unsigned short*)(ws + (long long)(65.5 * MB));
  unsigned short* qbuf  = (unsigned short*)(ws + (long long)(129.5 * MB));
  unsigned short* kbuf  = (unsigned short*)(ws + (long long)(193.5 * MB));
  unsigned short* vbuf  = (unsigned short*)(ws + (long long)(257.5 * MB));
  unsigned short* aoutb = kv_in;      // kv_in dead after kv GEMM -> alias
  unsigned short* xn    = vbuf;       // vbuf dead after attn_k -> alias
  unsigned short* Hh    = q_in;       // dead after gemm<2> -> alias (134MB)

  prep_w<<<3072, 256, 0, stream>>>(qw, kvw, pw, w1, w2, wb);
  ln1_win<<<65536, 256, 0, stream>>>(x, g1, b1, q_in, kv_in);
  gemm_bt<0, 1><<<1024, 512, 0, stream>>>(q_in, wb, qb, 0.17677669529663687f,
                                          qbuf, nullptr, nullptr, nullptr, nullptr);
  gemm_bt<1, 2><<<1024, 512, 0, stream>>>(kv_in, wb + 65536, kvb, 1.0f,
                                          kbuf, vbuf, nullptr, nullptr, nullptr);
  attn_k<<<16384, 64, 0, stream>>>(qbuf, kbuf, vbuf, mask, bias_table, aoutb);
  gemm_bt<2, 1><<<1024, 512, 0, stream>>>(aoutb, wb + 196608, pb, 1.0f,
                                          nullptr, nullptr, out, q_in, x);
  ln2_k<<<32768, 256, 0, stream>>>(out, g2, b2, xn);
  const unsigned short* w1b = wb + 262144;
  const unsigned short* w2b = wb + 524288;
  // M-sliced MLP: per half, GEMM1 over full hidden then one += pass on out.
  for (int h = 0; h < 2; h++){
    const long long R = (long long)h * 65536;
    mlp_gemm<4, 0, 0><<<dim3(8, 512), 256, 0, stream>>>(xn + R * 256, 256, w1b, 256,
                                                        bi1, Hh, 1024, nullptr);
    mlp_gemm<16, 1, 1><<<dim3(2, 512), 256, 0, stream>>>(Hh, 1024, w2b, 1024,
                                                         bi2, nullptr, 0, out + R * 256);
  }
}

// Round 11
// 768.891 us; speedup vs baseline: 1.4037x; 1.0783x over previous
//
#include <hip/hip_runtime.h>
#include <hip/hip_bf16.h>
#include <math.h>

#define SHIFT_ 4

typedef __attribute__((ext_vector_type(8))) short bh8;
typedef __attribute__((ext_vector_type(4))) short sh4;
typedef __attribute__((ext_vector_type(4))) float f4;
typedef __attribute__((ext_vector_type(8))) __bf16 bf8t;

static __device__ __forceinline__ f4 mfma16(bh8 a, bh8 b, f4 c){
  return __builtin_amdgcn_mfma_f32_16x16x32_bf16(
    __builtin_bit_cast(bf8t, a), __builtin_bit_cast(bf8t, b), c, 0, 0, 0);
}
static __device__ __forceinline__ unsigned short f2b(float f){
  unsigned u = __builtin_bit_cast(unsigned, f);
  u += 0x7fffu + ((u >> 16) & 1u);
  return (unsigned short)(u >> 16);
}
static __device__ __forceinline__ float b2f(unsigned short h){
  return __builtin_bit_cast(float, ((unsigned)h) << 16);
}
static __device__ __forceinline__ unsigned cvt_pk_bf16(float lo, float hi){
  unsigned r;
  asm("v_cvt_pk_bf16_f32 %0, %1, %2" : "=v"(r) : "v"(lo), "v"(hi));
  return r;
}
static __device__ __forceinline__ float gelu_f(float hv){
  float u = hv * (1.5957691216f + 0.0713548162f * hv * hv);
  return hv * __builtin_amdgcn_rcpf(1.f + __expf(-u));
}

// ---------------- kernel 0: weights f32 -> bf16 (qw pre-scaled by d^-0.5) ---
__global__ __launch_bounds__(256) void prep_w(
    const float* __restrict__ qw, const float* __restrict__ kvw,
    const float* __restrict__ pw, const float* __restrict__ w1,
    const float* __restrict__ w2, unsigned short* __restrict__ wb){
  int i = blockIdx.x * 256 + threadIdx.x;   // 786432 total
  float v;
  if      (i < 65536)  v = qw[i] * 0.17677669529663687f;
  else if (i < 196608) v = kvw[i - 65536];
  else if (i < 262144) v = pw[i - 196608];
  else if (i < 524288) v = w1[i - 262144];
  else                 v = w2[i - 524288];
  wb[i] = f2b(v);
}

// ---------------- kernel 1: LN1 + roll(-4,-4) + window partition ------------
__global__ __launch_bounds__(256) void ln1_win(
    const float* __restrict__ x, const float* __restrict__ g1,
    const float* __restrict__ b1,
    unsigned short* __restrict__ q_in, unsigned short* __restrict__ kv_in){
  int rid  = blockIdx.x * 4 + (threadIdx.x >> 6);   // 0..262143
  int lane = threadIdx.x & 63;
  int d    = rid >> 17;
  int rem  = rid & 131071;          // w*64 + n
  int w = rem >> 6, n = rem & 63;
  int b = w >> 10, hb = (w >> 5) & 31, wbk = w & 31;
  int sh = (hb * 8 + (n >> 3) + SHIFT_) & 255;
  int sw = (wbk * 8 + (n & 7) + SHIFT_) & 255;
  const float* src = x + ((((size_t)(b * 2 + d)) * 256 + sh) * 256 + sw) * 256;
  float4 v = *(const float4*)(src + lane * 4);
  float s  = v.x + v.y + v.z + v.w;
  float ss = v.x * v.x + v.y * v.y + v.z * v.z + v.w * v.w;
  #pragma unroll
  for (int off = 1; off < 64; off <<= 1){ s += __shfl_xor(s, off); ss += __shfl_xor(ss, off); }
  float m    = s * (1.f / 256.f);
  float rstd = rsqrtf(ss * (1.f / 256.f) - m * m + 1e-5f);
  int c = lane * 4;
  float4 g  = *(const float4*)(g1 + c);
  float4 bb = *(const float4*)(b1 + c);
  sh4 o;
  o.x = (short)f2b((v.x - m) * rstd * g.x + bb.x);
  o.y = (short)f2b((v.y - m) * rstd * g.y + bb.y);
  o.z = (short)f2b((v.z - m) * rstd * g.z + bb.z);
  o.w = (short)f2b((v.w - m) * rstd * g.w + bb.w);
  unsigned short* dst = (d == 0 ? q_in : kv_in) + (size_t)rem * 256 + c;
  *(sh4*)dst = o;
}

// ---------------- QKV/P GEMM, 512 thr, block 128 x (NT*256) -----------------
template<int MODE, int NT>
__global__ __launch_bounds__(512, 4) void gemm_bt(
    const unsigned short* __restrict__ A, const unsigned short* __restrict__ Wt,
    const float* __restrict__ bias, float bias_scale,
    unsigned short* __restrict__ outb, unsigned short* __restrict__ vpl,
    float* __restrict__ outf, const unsigned short* __restrict__ qin,
    const float* __restrict__ xsrc){
  __shared__ unsigned short sA[128][64];
  __shared__ unsigned short sB[256][64];
  int m0 = blockIdx.x * 128;
  int tid = threadIdx.x, lane = tid & 63, wid = tid >> 6;   // 8 waves
  int wm = wid >> 2, wn = wid & 3;
  int llo = lane & 15, lhi = lane >> 4;
  int lr = lane >> 3, lc = (lane & 7) * 8;
  const f4 FZ = {0.f, 0.f, 0.f, 0.f};
  for (int nt = 0; nt < NT; nt++){
    f4 acc[4][4];
    for (int i = 0; i < 4; i++) for (int j = 0; j < 4; j++) acc[i][j] = FZ;
    for (int t = 0; t < 4; t++){
      int k0 = t * 64;
      #pragma unroll
      for (int c = 0; c < 2; c++){
        int rr = wid * 16 + c * 8;
        __builtin_amdgcn_global_load_lds(
          (const __attribute__((address_space(1))) unsigned int*)(A + (size_t)(m0 + rr + lr) * 256 + k0 + lc),
          (__attribute__((address_space(3))) unsigned int*)&sA[rr][0], 16, 0, 0);
      }
      #pragma unroll
      for (int c = 0; c < 4; c++){
        int rb = wid * 32 + c * 8;
        __builtin_amdgcn_global_load_lds(
          (const __attribute__((address_space(1))) unsigned int*)(Wt + (size_t)(nt * 256 + rb + lr) * 256 + k0 + lc),
          (__attribute__((address_space(3))) unsigned int*)&sB[rb][0], 16, 0, 0);
      }
      __syncthreads();
      #pragma unroll
      for (int ks = 0; ks < 2; ks++){
        bh8 a[4], b[4];
        #pragma unroll
        for (int mi = 0; mi < 4; mi++) a[mi] = *(const bh8*)&sA[wm * 64 + mi * 16 + llo][ks * 32 + lhi * 8];
        #pragma unroll
        for (int nj = 0; nj < 4; nj++) b[nj] = *(const bh8*)&sB[wn * 64 + nj * 16 + llo][ks * 32 + lhi * 8];
        #pragma unroll
        for (int mi = 0; mi < 4; mi++)
          #pragma unroll
          for (int nj = 0; nj < 4; nj++){
            if (MODE < 2) acc[mi][nj] = mfma16(b[nj], a[mi], acc[mi][nj]);   // swapped
            else          acc[mi][nj] = mfma16(a[mi], b[nj], acc[mi][nj]);
          }
      }
      __syncthreads();
    }
    if (MODE < 2){
      #pragma unroll
      for (int nj = 0; nj < 4; nj++){
        int cb = wn * 64 + nj * 16 + lhi * 4;
        int col = nt * 256 + cb;
        float4 bv = *(const float4*)(bias + col);
        #pragma unroll
        for (int mi = 0; mi < 4; mi++){
          int row = m0 + wm * 64 + mi * 16 + llo;
          float f0 = acc[mi][nj][0] + bv.x * bias_scale;
          float f1 = acc[mi][nj][1] + bv.y * bias_scale;
          float f2 = acc[mi][nj][2] + bv.z * bias_scale;
          float f3 = acc[mi][nj][3] + bv.w * bias_scale;
          uint2 p;
          p.x = cvt_pk_bf16(f0, f1);
          p.y = cvt_pk_bf16(f2, f3);
          if (MODE == 0 || nt == 0) *(uint2*)(outb + (size_t)row * 256 + cb) = p;
          else                      *(uint2*)(vpl  + (size_t)row * 256 + cb) = p;
        }
      }
    } else {
      #pragma unroll
      for (int mi = 0; mi < 4; mi++)
        #pragma unroll
        for (int nj = 0; nj < 4; nj++){
          int col = wn * 64 + nj * 16 + llo;
          float bv = bias[col] * bias_scale;
          #pragma unroll
          for (int r = 0; r < 4; r++){
            int row = m0 + wm * 64 + mi * 16 + lhi * 4 + r;
            int w = row >> 6, n = row & 63;
            int b = w >> 10, hb = (w >> 5) & 31, wbk = w & 31;
            int hh = (hb * 8 + (n >> 3) + SHIFT_) & 255;
            int ww = (wbk * 8 + (n & 7) + SHIFT_) & 255;
            float res = b2f(qin[(size_t)row * 256 + col]);
            float sc  = xsrc[((((size_t)(b * 2)) * 256 + hh) * 256 + ww) * 256 + col];
            outf[(((size_t)b * 256 + hh) * 256 + ww) * 256 + col] = acc[mi][nj][r] + bv + res + sc;
          }
        }
    }
  }
}

// ---------------- kernel 3: attention, block = (window, 4-head group) -------
// 256 thr / 4 waves, wave = head. Mask staged ONCE (bf16 LDS), V transposed
// in LDS, Q/K fragments straight from global (consumed once). One barrier.
__global__ __launch_bounds__(256, 2) void attn_k(
    const unsigned short* __restrict__ q, const unsigned short* __restrict__ k,
    const unsigned short* __restrict__ v, const float* __restrict__ mask,
    const float* __restrict__ bias_table, unsigned short* __restrict__ aout){
  __shared__ unsigned short sMask[64][72];   // bf16 mask
  __shared__ unsigned short sVT[128][72];    // V^T (d-local x n) for this group
  __shared__ unsigned short sP[4][64][72];
  __shared__ float sBias[4][225];
  int bid = blockIdx.x;                      // 4096 = 2048 windows x 2 groups
  int w = bid >> 1, hg = bid & 1;
  int tid = threadIdx.x, lane = tid & 63, wid = tid >> 6;
  int hd = hg * 4 + wid;
  int llo = lane & 15, lhi = lane >> 4;
  // Q/K fragments direct from global (each element consumed once)
  const unsigned short* qp = q + (size_t)w * 64 * 256 + hd * 32;
  const unsigned short* kp = k + (size_t)w * 64 * 256 + hd * 32;
  bh8 af[4], bf[4];
  #pragma unroll
  for (int mi = 0; mi < 4; mi++) af[mi] = *(const bh8*)(qp + (size_t)(mi * 16 + llo) * 256 + lhi * 8);
  #pragma unroll
  for (int nj = 0; nj < 4; nj++) bf[nj] = *(const bh8*)(kp + (size_t)(nj * 16 + llo) * 256 + lhi * 8);
  // stage mask (f32 -> bf16) cooperatively
  const float* mrow = mask + (size_t)(w & 1023) * 4096;
  #pragma unroll
  for (int i = 0; i < 2; i++){
    int base = (tid + i * 256) * 8;          // 0..4088
    float4 u0 = *(const float4*)(mrow + base);
    float4 u1 = *(const float4*)(mrow + base + 4);
    int rr = base >> 6, cc = base & 63;
    uint4 p;
    p.x = cvt_pk_bf16(u0.x, u0.y); p.y = cvt_pk_bf16(u0.z, u0.w);
    p.z = cvt_pk_bf16(u1.x, u1.y); p.w = cvt_pk_bf16(u1.z, u1.w);
    *(uint4*)&sMask[rr][cc] = p;
  }
  // stage V transposed: read coalesced rows, scatter to sVT[d][n]
  {
    const unsigned short* vp = v + (size_t)w * 64 * 256 + hg * 128;
    #pragma unroll
    for (int it = 0; it < 4; it++){
      int idx = tid + it * 256;              // 0..1023
      int n = idx >> 4, dc = (idx & 15) * 8;
      bh8 vv = *(const bh8*)(vp + (size_t)n * 256 + dc);
      #pragma unroll
      for (int j = 0; j < 8; j++) sVT[dc + j][n] = (unsigned short)vv[j];
    }
  }
  // per-wave bias slice
  for (int i = lane; i < 225; i += 64) sBias[wid][i] = bias_table[i * 8 + hd];
  // QK^T while staging drains
  const f4 FZ = {0.f, 0.f, 0.f, 0.f};
  f4 acc[4][4];
  #pragma unroll
  for (int mi = 0; mi < 4; mi++)
    #pragma unroll
    for (int nj = 0; nj < 4; nj++)
      acc[mi][nj] = mfma16(af[mi], bf[nj], FZ);
  __syncthreads();   // sMask + sVT ready
  // softmax (reads LDS only) -> sP[wid]
  #pragma unroll
  for (int mi = 0; mi < 4; mi++){
    #pragma unroll
    for (int r = 0; r < 4; r++){
      int rr = mi * 16 + lhi * 4 + r;
      int yi = rr >> 3, xi = rr & 7;
      float sv[4]; float mx = -1e30f;
      #pragma unroll
      for (int nj = 0; nj < 4; nj++){
        int cc = nj * 16 + llo;
        int idx = (yi - (cc >> 3) + 7) * 15 + (xi - (cc & 7) + 7);
        sv[nj] = acc[mi][nj][r] + sBias[wid][idx] + b2f(sMask[rr][cc]);
        mx = fmaxf(mx, sv[nj]);
      }
      #pragma unroll
      for (int off = 1; off < 16; off <<= 1) mx = fmaxf(mx, __shfl_xor(mx, off));
      float sum = 0.f;
      #pragma unroll
      for (int nj = 0; nj < 4; nj++){ sv[nj] = __expf(sv[nj] - mx); sum += sv[nj]; }
      #pragma unroll
      for (int off = 1; off < 16; off <<= 1) sum += __shfl_xor(sum, off);
      float inv = __builtin_amdgcn_rcpf(sum);
      #pragma unroll
      for (int nj = 0; nj < 4; nj++) sP[wid][rr][nj * 16 + llo] = f2b(sv[nj] * inv);
    }
  }
  // PV (sP is wave-private; same-wave LDS ordering, no barrier needed)
  f4 o[4][2];
  for (int mi = 0; mi < 4; mi++) for (int dj = 0; dj < 2; dj++) o[mi][dj] = FZ;
  #pragma unroll
  for (int ks = 0; ks < 2; ks++){
    bh8 pa[4], vb[2];
    #pragma unroll
    for (int mi = 0; mi < 4; mi++) pa[mi] = *(const bh8*)&sP[wid][mi * 16 + llo][ks * 32 + lhi * 8];
    #pragma unroll
    for (int dj = 0; dj < 2; dj++) vb[dj] = *(const bh8*)&sVT[wid * 32 + dj * 16 + llo][ks * 32 + lhi * 8];
    #pragma unroll
    for (int mi = 0; mi < 4; mi++)
      #pragma unroll
      for (int dj = 0; dj < 2; dj++)
        o[mi][dj] = mfma16(pa[mi], vb[dj], o[mi][dj]);
  }
  #pragma unroll
  for (int mi = 0; mi < 4; mi++)
    for (int dj = 0; dj < 2; dj++)
      for (int r = 0; r < 4; r++){
        int rr = mi * 16 + lhi * 4 + r, dd = dj * 16 + llo;
        aout[((size_t)w * 64 + rr) * 256 + hd * 32 + dd] = f2b(o[mi][dj][r]);
      }
}

// ---------------- kernel 4: LN2 -> bf16 xn (row-major) ----------------------
__global__ __launch_bounds__(256) void ln2_k(
    const float* __restrict__ x1, const float* __restrict__ g2,
    const float* __restrict__ b2, unsigned short* __restrict__ xn){
  int rid  = blockIdx.x * 4 + (threadIdx.x >> 6);   // 0..131071
  int lane = threadIdx.x & 63;
  const float* xr = x1 + (size_t)rid * 256;
  float4 v = *(const float4*)(xr + lane * 4);
  float s  = v.x + v.y + v.z + v.w;
  float ss = v.x * v.x + v.y * v.y + v.z * v.z + v.w * v.w;
  #pragma unroll
  for (int off = 1; off < 64; off <<= 1){ s += __shfl_xor(s, off); ss += __shfl_xor(ss, off); }
  float m    = s * (1.f / 256.f);
  float rstd = rsqrtf(ss * (1.f / 256.f) - m * m + 1e-5f);
  int c = lane * 4;
  float4 g  = *(const float4*)(g2 + c);
  float4 bb = *(const float4*)(b2 + c);
  sh4 o;
  o.x = (short)f2b((v.x - m) * rstd * g.x + bb.x);
  o.y = (short)f2b((v.y - m) * rstd * g.y + bb.y);
  o.z = (short)f2b((v.z - m) * rstd * g.z + bb.z);
  o.w = (short)f2b((v.w - m) * rstd * g.w + bb.w);
  *(sh4*)(xn + (size_t)rid * 256 + c) = o;
}

// ---------------- kernel 5: m97-template GEMM for the MLP -------------------
template<int KSTEPS, int EPI, int BIASF>
__global__ __launch_bounds__(256, 3) void mlp_gemm(
    const unsigned short* __restrict__ A, int lda,
    const unsigned short* __restrict__ Bw, int ldb,
    const float* __restrict__ bias,
    unsigned short* __restrict__ outb, int ldo,
    float* __restrict__ outf){
  __shared__ unsigned short sA[128][64];
  __shared__ unsigned short sB[128][64];
  int n0 = blockIdx.x * 128, m0 = blockIdx.y * 128;
  int tid = threadIdx.x, lane = tid & 63, wid = tid >> 6;
  int wm = wid >> 1, wn = wid & 1;
  int llo = lane & 15, lhi = lane >> 4;
  int lr = lane >> 3, lc = (lane & 7) * 8;
  const f4 FZ = {0.f, 0.f, 0.f, 0.f};
  f4 acc[4][4];
  for (int i = 0; i < 4; i++) for (int j = 0; j < 4; j++) acc[i][j] = FZ;

  for (int t = 0; t < KSTEPS; t++){
    int k0 = t * 64;
    #pragma unroll
    for (int c = 0; c < 4; c++){
      int rr = wid * 32 + c * 8 + lr;
      __builtin_amdgcn_global_load_lds(
        (const __attribute__((address_space(1))) unsigned int*)(A + (size_t)(m0 + rr) * lda + k0 + lc),
        (__attribute__((address_space(3))) unsigned int*)&sA[wid * 32 + c * 8][0], 16, 0, 0);
      __builtin_amdgcn_global_load_lds(
        (const __attribute__((address_space(1))) unsigned int*)(Bw + (size_t)(n0 + rr) * ldb + k0 + lc),
        (__attribute__((address_space(3))) unsigned int*)&sB[wid * 32 + c * 8][0], 16, 0, 0);
    }
    __syncthreads();
    #pragma unroll
    for (int ks = 0; ks < 2; ks++){
      bh8 a[4], b[4];
      #pragma unroll
      for (int mi = 0; mi < 4; mi++) a[mi] = *(const bh8*)&sA[wm * 64 + mi * 16 + llo][ks * 32 + lhi * 8];
      #pragma unroll
      for (int nj = 0; nj < 4; nj++) b[nj] = *(const bh8*)&sB[wn * 64 + nj * 16 + llo][ks * 32 + lhi * 8];
      #pragma unroll
      for (int mi = 0; mi < 4; mi++)
        #pragma unroll
        for (int nj = 0; nj < 4; nj++){
          if (EPI == 0) acc[mi][nj] = mfma16(b[nj], a[mi], acc[mi][nj]);   // swapped
          else          acc[mi][nj] = mfma16(a[mi], b[nj], acc[mi][nj]);
        }
    }
    __syncthreads();
  }
  if (EPI == 0){
    #pragma unroll
    for (int nj = 0; nj < 4; nj++){
      int cb = n0 + wn * 64 + nj * 16 + lhi * 4;
      float4 bv = *(const float4*)(bias + cb);
      #pragma unroll
      for (int mi = 0; mi < 4; mi++){
        int row = m0 + wm * 64 + mi * 16 + llo;
        float g0 = gelu_f(acc[mi][nj][0] + bv.x);
        float g1 = gelu_f(acc[mi][nj][1] + bv.y);
        float g2 = gelu_f(acc[mi][nj][2] + bv.z);
        float g3 = gelu_f(acc[mi][nj][3] + bv.w);
        uint2 p;
        p.x = cvt_pk_bf16(g0, g1);
        p.y = cvt_pk_bf16(g2, g3);
        *(uint2*)(outb + (size_t)row * ldo + cb) = p;
      }
    }
  } else {
    #pragma unroll
    for (int mi = 0; mi < 4; mi++)
      #pragma unroll
      for (int nj = 0; nj < 4; nj++){
        int col = n0 + wn * 64 + nj * 16 + llo;
        float bv = BIASF ? bias[col] : 0.f;
        #pragma unroll
        for (int r = 0; r < 4; r++){
          int row = m0 + wm * 64 + mi * 16 + lhi * 4 + r;
          outf[(size_t)row * 256 + col] += acc[mi][nj][r] + bv;
        }
      }
  }
}

extern "C" void kernel_launch(void* const* d_in, const int* in_sizes, int n_in,
                              void* d_out, int out_size, void* d_ws, size_t ws_size,
                              hipStream_t stream){
  const float* x          = (const float*)d_in[0];
  const float* mask       = (const float*)d_in[1];
  const float* g1         = (const float*)d_in[2];
  const float* b1         = (const float*)d_in[3];
  const float* qw         = (const float*)d_in[4];
  const float* qb         = (const float*)d_in[5];
  const float* kvw        = (const float*)d_in[6];
  const float* kvb        = (const float*)d_in[7];
  const float* pw         = (const float*)d_in[8];
  const float* pb         = (const float*)d_in[9];
  const float* bias_table = (const float*)d_in[10];
  const float* g2         = (const float*)d_in[11];
  const float* b2         = (const float*)d_in[12];
  const float* w1         = (const float*)d_in[13];
  const float* bi1        = (const float*)d_in[14];
  const float* w2         = (const float*)d_in[15];
  const float* bi2        = (const float*)d_in[16];
  float* out = (float*)d_out;
  char* ws = (char*)d_ws;
  const long long MB = 1048576LL;
  unsigned short* wb    = (unsigned short*)(ws);
  unsigned short* q_in  = (unsigned short*)(ws + (long long)(1.5 * MB));
  unsigned short* kv_in = (unsigned short*)(ws + (long long)(65.5 * MB));
  unsigned short* qbuf  = (unsigned short*)(ws + (long long)(129.5 * MB));
  unsigned short* kbuf  = (unsigned short*)(ws + (long long)(193.5 * MB));
  unsigned short* vbuf  = (unsigned short*)(ws + (long long)(257.5 * MB));
  unsigned short* aoutb = kv_in;      // kv_in dead after kv GEMM -> alias
  unsigned short* xn    = vbuf;       // vbuf dead after attn_k -> alias
  unsigned short* Hh    = q_in;       // dead after gemm<2> -> alias (134MB)

  prep_w<<<3072, 256, 0, stream>>>(qw, kvw, pw, w1, w2, wb);
  ln1_win<<<65536, 256, 0, stream>>>(x, g1, b1, q_in, kv_in);
  gemm_bt<0, 1><<<1024, 512, 0, stream>>>(q_in, wb, qb, 0.17677669529663687f,
                                          qbuf, nullptr, nullptr, nullptr, nullptr);
  gemm_bt<1, 2><<<1024, 512, 0, stream>>>(kv_in, wb + 65536, kvb, 1.0f,
                                          kbuf, vbuf, nullptr, nullptr, nullptr);
  attn_k<<<4096, 256, 0, stream>>>(qbuf, kbuf, vbuf, mask, bias_table, aoutb);
  gemm_bt<2, 1><<<1024, 512, 0, stream>>>(aoutb, wb + 196608, pb, 1.0f,
                                          nullptr, nullptr, out, q_in, x);
  ln2_k<<<32768, 256, 0, stream>>>(out, g2, b2, xn);
  const unsigned short* w1b = wb + 262144;
  const unsigned short* w2b = wb + 524288;
  for (int h = 0; h < 2; h++){
    const long long R = (long long)h * 65536;
    mlp_gemm<4, 0, 0><<<dim3(8, 512), 256, 0, stream>>>(xn + R * 256, 256, w1b, 256,
                                                        bi1, Hh, 1024, nullptr);
    mlp_gemm<16, 1, 1><<<dim3(2, 512), 256, 0, stream>>>(Hh, 1024, w2b, 1024,
                                                         bi2, nullptr, 0, out + R * 256);
  }
}